// Round 8
// baseline (505.838 us; speedup 1.0000x reference)
//
#include <hip/hip_runtime.h>
#include <cstdint>
#include <cstddef>

#define B_   8
#define S_   2048
#define H_   1024
#define K3_  3072              // 3*H
#define SC_  512               // chunk length
#define TB_  (SC_ / 4)         // 128 t-blocks (of 4 timesteps) per chunk
#define WSCALE 32.0f           // pre-scale W so f16 lo-plane stays normal-range
#define NGEMM_ 192             // (4096/256) * (3072/256)

typedef __attribute__((ext_vector_type(8))) _Float16 f16x8;
typedef __attribute__((ext_vector_type(4))) _Float16 f16x4;
typedef __attribute__((ext_vector_type(4))) float f32x4;
typedef __attribute__((ext_vector_type(16))) float f32x16;

// U layout: t-interleaved-transposed U4[b][tb][k3][4] (tb=t>>2): GEMM epilogue stores
// float4 (full-line coalesced), scan reads float4 = 4 timesteps/channel.

// --------------------------------------------- cast body (256-thr blocks; prep + fallback)
__device__ __forceinline__ void cast_body(const float4* __restrict__ X,
                                          f16x4* __restrict__ Xh, f16x4* __restrict__ Xl,
                                          int ci, int tid, int s0) {
    const int nthr = (B_ * SC_ * H_) >> 4;
    int i0 = ci * 256 + tid;
#pragma unroll
    for (int u = 0; u < 4; ++u) {
        int i  = i0 + u * nthr;
        int r  = i >> 8;
        int c4 = i & 255;
        int b  = r >> 9;
        int sl = r & (SC_ - 1);
        size_t src = ((size_t)b * S_ + s0 + sl) * (H_ / 4) + c4;
        float4 v = X[src];
        _Float16 h0 = (_Float16)v.x, h1 = (_Float16)v.y, h2 = (_Float16)v.z, h3 = (_Float16)v.w;
        f16x4 hv = {h0, h1, h2, h3};
        f16x4 lv = {(_Float16)(v.x - (float)h0), (_Float16)(v.y - (float)h1),
                    (_Float16)(v.z - (float)h2), (_Float16)(v.w - (float)h3)};
        size_t dst = ((size_t)b * SC_ + sl) * (H_ / 4) + c4;
        Xh[dst] = hv;
        Xl[dst] = lv;
    }
}

// --------------------------------------------- standalone cast (small-ws fallback path)
__global__ __launch_bounds__(256) void castx_kernel(const float4* __restrict__ X,
                                                    f16x4* __restrict__ Xh,
                                                    f16x4* __restrict__ Xl, int s0) {
    cast_body(X, Xh, Xl, blockIdx.x, threadIdx.x, s0);
}

// --------------------------------------------- prep: transW (blocks 0..3071) + cast chunk0
__global__ __launch_bounds__(256) void prep_kernel(const float* __restrict__ W,
                                                   _Float16* __restrict__ Wth,
                                                   _Float16* __restrict__ Wtl,
                                                   const float4* __restrict__ X,
                                                   f16x4* __restrict__ Xh,
                                                   f16x4* __restrict__ Xl) {
    __shared__ float tile[32][33];
    if ((int)blockIdx.x < 3072) {
        int idx = blockIdx.x;
        int bc  = (idx % 96) * 32;
        int brr = (idx / 96) * 32;
        int tx = threadIdx.x & 31;
        int ty = threadIdx.x >> 5;
#pragma unroll
        for (int i = 0; i < 4; ++i) {
            int r = ty + i * 8;
            tile[r][tx] = W[(size_t)(brr + r) * K3_ + bc + tx];
        }
        __syncthreads();
#pragma unroll
        for (int i = 0; i < 4; ++i) {
            int r = ty + i * 8;
            float v = tile[tx][r] * WSCALE;
            _Float16 h = (_Float16)v;
            _Float16 l = (_Float16)(v - (float)h);
            Wth[(size_t)(bc + r) * H_ + brr + tx] = h;
            Wtl[(size_t)(bc + r) * H_ + brr + tx] = l;
        }
    } else {
        cast_body(X, Xh, Xl, (int)blockIdx.x - 3072, threadIdx.x, 0);
    }
}

// ---------------------------------------------------------------- fused GEMM + scan + cast
// Grid (big-ws): 32 scan + 192 GEMM + 32 cast = 256 blocks x 512 thr = 1 block/CU.
// GEMM: 256x256 tile, BK=32, 8 waves (2M x 4N), double-buffered LDS (128 KB),
// counted vmcnt(8) (never drain 0 in loop) + raw s_barrier — T3/T4 schedule.
// R8: 32x32x16 MFMA (2495 TF ceiling vs 2075 for 16x16x32, m119/m06) — 17% lower
// MFMA floor and half the MFMA instruction count (48 vs 96 per wave per k-tile).
// Fragment layout: A/B 8 f16/lane at [row=lane&31][k=(lane>>5)*8+e]; C/D:
// col=lane&31, row=(reg&3)+8*(reg>>2)+4*(lane>>5) (HW-verified m74/m101).
__global__ __launch_bounds__(512, 2) void fused_kernel(
        const _Float16* __restrict__ Ah, const _Float16* __restrict__ Al,
        const _Float16* __restrict__ Bh, const _Float16* __restrict__ Bl,
        float* __restrict__ C, int nGemm,
        const float* __restrict__ Uprev, int s0scan, int nScan,
        const float* __restrict__ X,
        f16x4* __restrict__ Xch, f16x4* __restrict__ Xcl, int s0cast,
        const float* __restrict__ vf,  const float* __restrict__ vr,
        const float* __restrict__ bfv, const float* __restrict__ brv,
        float* __restrict__ Y, float* __restrict__ carry) {
    // [dbuf][mat: Ah,Al,Bh,Bl][256 rows x 32 k] f16 = 131072 B
    __shared__ _Float16 SH[2][4][256 * 32];

    const int tid = threadIdx.x;

    if ((int)blockIdx.x < nScan) {
        // ---------------- scan path (previous chunk), hidden under the GEMM ----------------
        if (tid >= 256) return;                     // waves 4..7 idle (no barriers here)
        int gid = blockIdx.x * 256 + tid;           // 0..8191 channel
        int b = gid >> 10;
        int h = gid & 1023;
        float vfh = vf[h], vrh = vr[h], bfh = bfv[h], brh = brv[h];
        const float* Ub4 = Uprev + ((size_t)(b * TB_) * K3_ + h) * 4;
        const float* Xb = X + ((size_t)b * S_ + s0scan) * H_ + h;
        float* Yb = Y + ((size_t)b * S_ + s0scan) * H_ + h;
        float c = (s0scan == 0) ? 0.f : carry[gid];

        float Af[8], Ac[8], Ar[8], Ax[8];
        float Bf[8], Bc[8], Br[8], Bx[8];
        auto LOAD = [&](int t0, float (&sf)[8], float (&sc)[8], float (&sr)[8], float (&sx)[8]) {
#pragma unroll
            for (int q = 0; q < 2; ++q) {
                const float* up = Ub4 + (size_t)((t0 >> 2) + q) * (K3_ * 4);
                float4 a  = *(const float4*)(up);
                float4 bb = *(const float4*)(up + H_ * 4);
                float4 cc = *(const float4*)(up + 2 * H_ * 4);
                sf[q*4+0]=a.x;  sf[q*4+1]=a.y;  sf[q*4+2]=a.z;  sf[q*4+3]=a.w;
                sc[q*4+0]=bb.x; sc[q*4+1]=bb.y; sc[q*4+2]=bb.z; sc[q*4+3]=bb.w;
                sr[q*4+0]=cc.x; sr[q*4+1]=cc.y; sr[q*4+2]=cc.z; sr[q*4+3]=cc.w;
            }
#pragma unroll
            for (int u = 0; u < 8; ++u) sx[u] = Xb[(size_t)(t0 + u) * H_];
        };
        auto COMP = [&](int t0, float (&sf)[8], float (&sc)[8], float (&sr)[8], float (&sx)[8]) {
#pragma unroll
            for (int u = 0; u < 8; ++u) {
                float zf = sf[u] + bfh + vfh * c;
                float zr = sr[u] + brh + vrh * c;
                float xc = sc[u];
                float ft = __builtin_amdgcn_rcpf(1.f + __expf(-zf));
                float rt = __builtin_amdgcn_rcpf(1.f + __expf(-zr));
                c = ft * (c - xc) + xc;
                float xv = sx[u];
                float ht = rt * (c - xv) + xv;
                Yb[(size_t)(t0 + u) * H_] = ht;
            }
        };
        LOAD(0, Af, Ac, Ar, Ax);
        for (int t0 = 0; t0 < SC_; t0 += 16) {
            LOAD(t0 + 8, Bf, Bc, Br, Bx);
            COMP(t0, Af, Ac, Ar, Ax);
            if (t0 + 16 < SC_) LOAD(t0 + 16, Af, Ac, Ar, Ax);
            COMP(t0 + 8, Bf, Bc, Br, Bx);
        }
        carry[gid] = c;
        return;
    }

    if ((int)blockIdx.x >= nScan + nGemm) {
        // ---------------- cast path (next chunk), hidden under the GEMM ----------------
        if (s0cast < 0) return;
        int ci = (int)blockIdx.x - nScan - nGemm;   // 0..31
        const float4* X4p = (const float4*)X;
        int gid0 = ci * 512 + tid;                  // 0..16383
#pragma unroll 4
        for (int u = 0; u < 64; ++u) {
            int i  = gid0 + u * 16384;              // 0..1048575
            int r  = i >> 8;
            int c4 = i & 255;
            int b  = r >> 9;
            int sl = r & (SC_ - 1);
            float4 v = X4p[((size_t)b * S_ + s0cast + sl) * (H_ / 4) + c4];
            _Float16 h0 = (_Float16)v.x, h1 = (_Float16)v.y, h2 = (_Float16)v.z, h3 = (_Float16)v.w;
            f16x4 hv = {h0, h1, h2, h3};
            f16x4 lv = {(_Float16)(v.x - (float)h0), (_Float16)(v.y - (float)h1),
                        (_Float16)(v.z - (float)h2), (_Float16)(v.w - (float)h3)};
            size_t dst = ((size_t)b * SC_ + sl) * (H_ / 4) + c4;
            Xch[dst] = hv;
            Xcl[dst] = lv;
        }
        return;
    }

    // ---------------- GEMM path: U[m,n] = (1/WSCALE) * (AlBh + AhBl + AhBh) ----------------
    const int idxg = (int)blockIdx.x - nScan;       // 0..191
    const int bm   = (idxg / 12) * 256;
    const int bn   = (idxg % 12) * 256;
    const int lane = tid & 63;
    const int w    = tid >> 6;                      // 0..7
    const int wm   = (w >> 2) * 128;                // 2 M-rows of waves
    const int wn   = (w & 3) * 64;                  // 4 N-cols of waves
    const int K    = 1024;

    const int l31 = lane & 31;
    const int lhi = lane >> 5;                      // 0/1: k-half within a 16-k step

    // per-wave output: 128x64 = 4 M-tiles x 2 N-tiles of 32x32
    f32x16 acc[4][2];
#pragma unroll
    for (int i = 0; i < 4; ++i)
#pragma unroll
        for (int j = 0; j < 2; ++j)
            acc[i][j] = (f32x16)(0.f);

    // k-invariant LDS byte offsets (XOR involution applied).
    // quad index within the 64B row = ks*2 + lhi (ks = 16-k step within BK=32).
    unsigned offA32[4][2], offB32[2][2];
#pragma unroll
    for (int mt = 0; mt < 4; ++mt) {
        int r = wm + mt * 32 + l31;
#pragma unroll
        for (int ks = 0; ks < 2; ++ks)
            offA32[mt][ks] = (unsigned)r * 64u +
                             (unsigned)(((ks * 2 + lhi) ^ ((r >> 1) & 3)) << 4);
    }
#pragma unroll
    for (int nt = 0; nt < 2; ++nt) {
        int r = wn + nt * 32 + l31;
#pragma unroll
        for (int ks = 0; ks < 2; ++ks)
            offB32[nt][ks] = (unsigned)r * 64u +
                             (unsigned)(((ks * 2 + lhi) ^ ((r >> 1) & 3)) << 4);
    }

    // STAGE: tile kt (K-offset kt*32) into buffer bi. 8 global_load_lds per thread
    // (FIFO: Ah,Al,Bh,Bl x2). XOR swizzle on the GLOBAL source column-quad
    // (global_load_lds dest must stay linear); reads apply the same involution.
    auto STAGE = [&](int kt, int bi) {
        int kk = kt * 32;
#pragma unroll
        for (int j = 0; j < 2; ++j) {
            int idx = j * 512 + tid;                // 0..1023
            int row = idx >> 2;                     // 0..255
            int kp  = (((idx & 3) ^ ((row >> 1) & 3)) << 3);
            size_t aoff = (size_t)(bm + row) * K + kk + kp;
            size_t boff = (size_t)(bn + row) * K + kk + kp;
            unsigned base = (unsigned)(j * 512 + (tid & ~63)) * 16u;  // wave-uniform bytes
            __builtin_amdgcn_global_load_lds(
                (const __attribute__((address_space(1))) void*)(Ah + aoff),
                (__attribute__((address_space(3))) void*)((char*)&SH[bi][0][0] + base), 16, 0, 0);
            __builtin_amdgcn_global_load_lds(
                (const __attribute__((address_space(1))) void*)(Al + aoff),
                (__attribute__((address_space(3))) void*)((char*)&SH[bi][1][0] + base), 16, 0, 0);
            __builtin_amdgcn_global_load_lds(
                (const __attribute__((address_space(1))) void*)(Bh + boff),
                (__attribute__((address_space(3))) void*)((char*)&SH[bi][2][0] + base), 16, 0, 0);
            __builtin_amdgcn_global_load_lds(
                (const __attribute__((address_space(1))) void*)(Bl + boff),
                (__attribute__((address_space(3))) void*)((char*)&SH[bi][3][0] + base), 16, 0, 0);
        }
    };

    // COMPUTE: per 16-k step, hoist fragments then 3 term-major passes of 8 MFMAs.
    // Dependent MFMAs on the same acc are 8 independent MFMAs apart (~258 cyc).
    // Per-acc term order: lbh -> hbl -> hbh (unchanged).
    auto COMPUTE = [&](int bi) {
        const char* pAh = (const char*)&SH[bi][0][0];
        const char* pAl = (const char*)&SH[bi][1][0];
        const char* pBh = (const char*)&SH[bi][2][0];
        const char* pBl = (const char*)&SH[bi][3][0];
#pragma unroll
        for (int ks = 0; ks < 2; ++ks) {
            f16x8 bh2[2], bl2[2], ah4[4], al4[4];
#pragma unroll
            for (int nt = 0; nt < 2; ++nt) {
                bh2[nt] = *(const f16x8*)(pBh + offB32[nt][ks]);
                bl2[nt] = *(const f16x8*)(pBl + offB32[nt][ks]);
            }
#pragma unroll
            for (int mt = 0; mt < 4; ++mt) {
                ah4[mt] = *(const f16x8*)(pAh + offA32[mt][ks]);
                al4[mt] = *(const f16x8*)(pAl + offA32[mt][ks]);
            }
#pragma unroll
            for (int mt = 0; mt < 4; ++mt)
#pragma unroll
                for (int nt = 0; nt < 2; ++nt)
                    acc[mt][nt] = __builtin_amdgcn_mfma_f32_32x32x16_f16(
                        al4[mt], bh2[nt], acc[mt][nt], 0, 0, 0);
#pragma unroll
            for (int mt = 0; mt < 4; ++mt)
#pragma unroll
                for (int nt = 0; nt < 2; ++nt)
                    acc[mt][nt] = __builtin_amdgcn_mfma_f32_32x32x16_f16(
                        ah4[mt], bl2[nt], acc[mt][nt], 0, 0, 0);
#pragma unroll
            for (int mt = 0; mt < 4; ++mt)
#pragma unroll
                for (int nt = 0; nt < 2; ++nt)
                    acc[mt][nt] = __builtin_amdgcn_mfma_f32_32x32x16_f16(
                        ah4[mt], bh2[nt], acc[mt][nt], 0, 0, 0);
        }
    };

    // prologue: 2 K-tiles in flight
    STAGE(0, 0);
    STAGE(1, 1);
    // main loop: wait ONLY the oldest tile (8 newer loads stay in flight across barriers)
    for (int t = 0; t < 31; ++t) {
        asm volatile("s_waitcnt vmcnt(8)" ::: "memory");
        __builtin_amdgcn_s_barrier();               // tile t fully in LDS (all waves)
        __builtin_amdgcn_sched_barrier(0);          // keep COMPUTE reads below the barrier
        COMPUTE(t & 1);
        __builtin_amdgcn_sched_barrier(0);          // keep reads above the next barrier
        __builtin_amdgcn_s_barrier();               // all waves done reading buf[t&1]
        __builtin_amdgcn_sched_barrier(0);          // keep STAGE writes below the barrier
        if (t < 30) STAGE(t + 2, t & 1);            // overwrite freed buffer
    }
    asm volatile("s_waitcnt vmcnt(0)" ::: "memory");
    __builtin_amdgcn_s_barrier();
    __builtin_amdgcn_sched_barrier(0);
    COMPUTE(1);                                     // tile 31

    // epilogue: C/D 32x32 layout -> U4: reg group g = rows 8g+4*lhi..+3 at col l31.
    // One float4 store per group (full-line coalesced across the 32-lane col range).
    const float inv = 1.0f / WSCALE;
#pragma unroll
    for (int mt = 0; mt < 4; ++mt)
#pragma unroll
        for (int nt = 0; nt < 2; ++nt)
#pragma unroll
            for (int g = 0; g < 4; ++g) {
                int row = bm + wm + mt * 32 + g * 8 + lhi * 4;   // multiple of 4
                int col = bn + wn + nt * 32 + l31;
                float4 v = {acc[mt][nt][g * 4 + 0] * inv, acc[mt][nt][g * 4 + 1] * inv,
                            acc[mt][nt][g * 4 + 2] * inv, acc[mt][nt][g * 4 + 3] * inv};
                *(float4*)(C + ((size_t)(row >> 2) * K3_ + col) * 4) = v;
            }
}

// ---------------------------------------------------------------- standalone scan (final chunk)
// 256 blocks x 32 active lanes. U read as coalesced float4 (U4 layout); x read direct
// (half-wave 128B coalesced dwords).
__global__ __launch_bounds__(64, 1) void scan_final_kernel(const float* __restrict__ U4,
                                                           const float* __restrict__ X,
                                                           const float* __restrict__ vf,
                                                           const float* __restrict__ vr,
                                                           const float* __restrict__ bfv,
                                                           const float* __restrict__ brv,
                                                           float* __restrict__ Y,
                                                           float* __restrict__ Cf,
                                                           const float* __restrict__ carry,
                                                           int s0) {
    int lane = threadIdx.x;
    if (lane >= 32) return;
    int gid = blockIdx.x * 32 + lane;          // 0..8191
    int b = gid >> 10;
    int h = gid & 1023;
    float vfh = vf[h], vrh = vr[h], bfh = bfv[h], brh = brv[h];
    const float* Ub4 = U4 + ((size_t)(b * TB_) * K3_ + h) * 4;
    const float* Xb = X + ((size_t)b * S_ + s0) * H_ + h;
    float* Yb = Y + ((size_t)b * S_ + s0) * H_ + h;
    float c = carry[gid];

    float Af[8], Ac[8], Ar[8], Ax[8];
    float Bf[8], Bc[8], Br[8], Bx[8];
    float Cg[8], Cc[8], Cr[8], Cx[8];
    float Df[8], Dc[8], Dr[8], Dx[8];

    auto LOAD = [&](int t0, float (&sf)[8], float (&sc)[8], float (&sr)[8], float (&sx)[8]) {
#pragma unroll
        for (int q = 0; q < 2; ++q) {
            size_t tb = (size_t)((t0 >> 2) + q);
            const float* up = Ub4 + tb * (K3_ * 4);
            float4 a  = *(const float4*)(up);
            float4 bb = *(const float4*)(up + H_ * 4);
            float4 cc = *(const float4*)(up + 2 * H_ * 4);
            sf[q*4+0]=a.x;  sf[q*4+1]=a.y;  sf[q*4+2]=a.z;  sf[q*4+3]=a.w;
            sc[q*4+0]=bb.x; sc[q*4+1]=bb.y; sc[q*4+2]=bb.z; sc[q*4+3]=bb.w;
            sr[q*4+0]=cc.x; sr[q*4+1]=cc.y; sr[q*4+2]=cc.z; sr[q*4+3]=cc.w;
        }
#pragma unroll
        for (int u = 0; u < 8; ++u) sx[u] = Xb[(size_t)(t0 + u) * H_];
    };
    auto COMP = [&](int t0, float (&sf)[8], float (&sc)[8], float (&sr)[8], float (&sx)[8]) {
#pragma unroll
        for (int u = 0; u < 8; ++u) {
            float zf = sf[u] + bfh + vfh * c;
            float zr = sr[u] + brh + vrh * c;
            float xc = sc[u];
            float ft = __builtin_amdgcn_rcpf(1.f + __expf(-zf));
            float rt = __builtin_amdgcn_rcpf(1.f + __expf(-zr));
            c = ft * (c - xc) + xc;
            float xv = sx[u];
            float ht = rt * (c - xv) + xv;
            Yb[(size_t)(t0 + u) * H_] = ht;
        }
    };

    LOAD(0, Af, Ac, Ar, Ax);
    LOAD(8, Bf, Bc, Br, Bx);
    LOAD(16, Cg, Cc, Cr, Cx);
    for (int t0 = 0; t0 < SC_; t0 += 32) {
        LOAD(t0 + 24, Df, Dc, Dr, Dx);
        COMP(t0, Af, Ac, Ar, Ax);
        if (t0 + 32 < SC_) LOAD(t0 + 32, Af, Ac, Ar, Ax);
        COMP(t0 + 8, Bf, Bc, Br, Bx);
        if (t0 + 40 < SC_) LOAD(t0 + 40, Bf, Bc, Br, Bx);
        COMP(t0 + 16, Cg, Cc, Cr, Cx);
        if (t0 + 48 < SC_) LOAD(t0 + 48, Cg, Cc, Cr, Cx);
        COMP(t0 + 24, Df, Dc, Dr, Dx);
    }
    Cf[(size_t)b * H_ + h] = c;
}

// ---------------------------------------------------------------- launcher
extern "C" void kernel_launch(void* const* d_in, const int* in_sizes, int n_in,
                              void* d_out, int out_size, void* d_ws, size_t ws_size,
                              hipStream_t stream) {
    const float* x  = (const float*)d_in[0];
    const float* W  = (const float*)d_in[1];
    const float* vf = (const float*)d_in[2];
    const float* vr = (const float*)d_in[3];
    const float* bf = (const float*)d_in[4];
    const float* br = (const float*)d_in[5];
    float* y  = (float*)d_out;
    float* cf = y + (size_t)B_ * S_ * H_;

    // ws layout (bytes):
    //   U0 @0            50,331,648
    //   U1 @50,331,648   50,331,648
    //   xh0 @100,663,296  8,388,608
    //   xl0 @109,051,904  8,388,608
    //   Wth @117,440,512  6,291,456
    //   Wtl @123,731,968  6,291,456
    //   carry @130,023,424   32,768
    //   xh1 @130,056,192  8,388,608   (big-ws only)
    //   xl1 @138,444,800  8,388,608   (end 146,833,408 — confirmed available)
    char* base = (char*)d_ws;
    float* U0 = (float*)base;
    float* U1 = (float*)(base + 50331648);
    _Float16* xh0 = (_Float16*)(base + 100663296);
    _Float16* xl0 = (_Float16*)(base + 109051904);
    _Float16* Wth = (_Float16*)(base + 117440512);
    _Float16* Wtl = (_Float16*)(base + 123731968);
    float* carry  = (float*)(base + 130023424);
    _Float16* xh1 = (_Float16*)(base + 130056192);
    _Float16* xl1 = (_Float16*)(base + 138444800);

    const bool big = ws_size >= 146833408ULL;      // constant across calls -> graph-safe
    float* Ubuf[2] = {U0, U1};
    _Float16* Xh[2] = {xh0, big ? xh1 : xh0};
    _Float16* Xl[2] = {xl0, big ? xl1 : xl0};

    // prep: transW + cast chunk0 into xbuf0
    prep_kernel<<<3072 + 1024, 256, 0, stream>>>(W, Wth, Wtl, (const float4*)x,
                                                 (f16x4*)xh0, (f16x4*)xl0);

    for (int i = 0; i < 4; ++i) {
        const int nScan = (i >= 1) ? 32 : 0;
        int nCast = 0, s0C = -1, nxt = i;
        if (big && i < 3) {
            nxt   = i + 1;
            nCast = 32;                            // 32 cast blocks x 512 thr x 64 f4
            s0C   = nxt * SC_;
        } else if (!big && i >= 1) {
            castx_kernel<<<1024, 256, 0, stream>>>((const float4*)x, (f16x4*)xh0,
                                                   (f16x4*)xl0, i * SC_);
        }
        const _Float16* Ahp = Xh[big ? (i & 1) : 0];
        const _Float16* Alp = Xl[big ? (i & 1) : 0];
        fused_kernel<<<nScan + NGEMM_ + nCast, 512, 0, stream>>>(
            Ahp, Alp, Wth, Wtl, Ubuf[i & 1], NGEMM_,
            (i >= 1) ? Ubuf[(i - 1) & 1] : Ubuf[0],
            (i >= 1) ? (i - 1) * SC_ : 0, nScan,
            x, (f16x4*)Xh[nxt & 1], (f16x4*)Xl[nxt & 1], s0C,
            vf, vr, bf, br, y, carry);
    }

    // final scan: chunk 3, U4 coalesced + direct x, writes Cf
    scan_final_kernel<<<256, 64, 0, stream>>>(Ubuf[1], x, vf, vr, bf, br, y, cf, carry, 3 * SC_);
}

// Round 9
// 482.887 us; speedup vs baseline: 1.0475x; 1.0475x over previous
//
#include <hip/hip_runtime.h>
#include <cstdint>
#include <cstddef>

#define B_   8
#define S_   2048
#define H_   1024
#define K3_  3072              // 3*H
#define SC_  512               // chunk length
#define TB_  (SC_ / 4)         // 128 t-blocks (of 4 timesteps) per chunk
#define WSCALE 32.0f           // pre-scale W so f16 lo-plane stays normal-range
#define NGEMM_ 192             // (4096/256) * (3072/256)

typedef __attribute__((ext_vector_type(8))) _Float16 f16x8;
typedef __attribute__((ext_vector_type(4))) _Float16 f16x4;
typedef __attribute__((ext_vector_type(4))) float f32x4;

// U layout: t-interleaved-transposed U4[b][tb][k3][4] (tb=t>>2): GEMM epilogue stores
// float4 (full-line coalesced), scan reads float4 = 4 timesteps/channel.
// X4 layout (chunk 3 only): X4[b][tb][h][4] — scan_final reads x as float4 too,
// cutting its per-8-step request count 14 -> 8 (the outstanding-request cap was
// throttling bytes-in-flight; R8 post-mortem).

// --------------------------------------------- cast body (256-thr blocks; prep + fallback)
__device__ __forceinline__ void cast_body(const float4* __restrict__ X,
                                          f16x4* __restrict__ Xh, f16x4* __restrict__ Xl,
                                          int ci, int tid, int s0) {
    const int nthr = (B_ * SC_ * H_) >> 4;
    int i0 = ci * 256 + tid;
#pragma unroll
    for (int u = 0; u < 4; ++u) {
        int i  = i0 + u * nthr;
        int r  = i >> 8;
        int c4 = i & 255;
        int b  = r >> 9;
        int sl = r & (SC_ - 1);
        size_t src = ((size_t)b * S_ + s0 + sl) * (H_ / 4) + c4;
        float4 v = X[src];
        _Float16 h0 = (_Float16)v.x, h1 = (_Float16)v.y, h2 = (_Float16)v.z, h3 = (_Float16)v.w;
        f16x4 hv = {h0, h1, h2, h3};
        f16x4 lv = {(_Float16)(v.x - (float)h0), (_Float16)(v.y - (float)h1),
                    (_Float16)(v.z - (float)h2), (_Float16)(v.w - (float)h3)};
        size_t dst = ((size_t)b * SC_ + sl) * (H_ / 4) + c4;
        Xh[dst] = hv;
        Xl[dst] = lv;
    }
}

// --------------------------------------------- xpose tile: one 32(t) x 32(h) tile -> X4
// 256-thread team; caller provides a 32x33 float LDS scratch. Two __syncthreads per call
// (all teams in a block must call in lockstep).
__device__ __forceinline__ void xpose_tile(const float* __restrict__ X, float* __restrict__ X4,
                                           int tg, int ttid, int s0, float (*tile)[33]) {
    int tx = ttid & 31, ty = ttid >> 5;    // ty 0..7
    int b    = tg >> 9;                    // 512 tiles per batch
    int tt   = tg & 511;
    int tb32 = tt >> 5;                    // 32-step t block, 0..15
    int hb   = tt & 31;                    // 32-ch h block, 0..31
#pragma unroll
    for (int i2 = 0; i2 < 4; ++i2) {
        int t = tb32 * 32 + ty + i2 * 8;
        tile[ty + i2 * 8][tx] = X[((size_t)b * S_ + s0 + t) * H_ + hb * 32 + tx];
    }
    __syncthreads();
    int h  = hb * 32 + tx;
    int tb = tb32 * 8 + ty;                // tb within chunk
    float4 v = {tile[ty * 4 + 0][tx], tile[ty * 4 + 1][tx],
                tile[ty * 4 + 2][tx], tile[ty * 4 + 3][tx]};
    *(float4*)(X4 + ((size_t)(b * TB_ + tb) * H_ + h) * 4) = v;
    __syncthreads();
}

// --------------------------------------------- standalone cast (small-ws fallback path)
__global__ __launch_bounds__(256) void castx_kernel(const float4* __restrict__ X,
                                                    f16x4* __restrict__ Xh,
                                                    f16x4* __restrict__ Xl, int s0) {
    cast_body(X, Xh, Xl, blockIdx.x, threadIdx.x, s0);
}

// --------------------------------------------- standalone x-transpose (small-ws fallback)
__global__ __launch_bounds__(256) void xpose_kernel(const float* __restrict__ X,
                                                    float* __restrict__ X4, int s0) {
    __shared__ float tile[32][33];
#pragma unroll
    for (int it = 0; it < 4; ++it)
        xpose_tile(X, X4, (int)blockIdx.x * 4 + it, threadIdx.x, s0, tile);
}

// --------------------------------------------- prep: transW (blocks 0..3071) + cast chunk0
__global__ __launch_bounds__(256) void prep_kernel(const float* __restrict__ W,
                                                   _Float16* __restrict__ Wth,
                                                   _Float16* __restrict__ Wtl,
                                                   const float4* __restrict__ X,
                                                   f16x4* __restrict__ Xh,
                                                   f16x4* __restrict__ Xl) {
    __shared__ float tile[32][33];
    if ((int)blockIdx.x < 3072) {
        int idx = blockIdx.x;
        int bc  = (idx % 96) * 32;
        int brr = (idx / 96) * 32;
        int tx = threadIdx.x & 31;
        int ty = threadIdx.x >> 5;
#pragma unroll
        for (int i = 0; i < 4; ++i) {
            int r = ty + i * 8;
            tile[r][tx] = W[(size_t)(brr + r) * K3_ + bc + tx];
        }
        __syncthreads();
#pragma unroll
        for (int i = 0; i < 4; ++i) {
            int r = ty + i * 8;
            float v = tile[tx][r] * WSCALE;
            _Float16 h = (_Float16)v;
            _Float16 l = (_Float16)(v - (float)h);
            Wth[(size_t)(bc + r) * H_ + brr + tx] = h;
            Wtl[(size_t)(bc + r) * H_ + brr + tx] = l;
        }
    } else {
        cast_body(X, Xh, Xl, (int)blockIdx.x - 3072, threadIdx.x, 0);
    }
}

// ---------------------------------------------------------------- fused GEMM + scan + cast/xpose
// Grid (big-ws): 32 scan + 192 GEMM + 32 aux = 256 blocks x 512 thr = 1 block/CU.
// GEMM: 256x256 tile, BK=32, 8 waves (2M x 4N), double-buffered LDS (128 KB),
// counted vmcnt(8) (never drain 0 in loop) + raw s_barrier — T3/T4 schedule.
// R7 COMPUTE: 16x16x32 MFMA, term-major per i-half (0 bank conflicts; R8's 32x32
// variant is structurally 4-way-conflicted with 64B LDS rows — reverted).
// aux blocks: cast of NEXT chunk (xtMode=0) or x-transpose of chunk 3 into Xt4
// (xtMode=1, i=3's otherwise-idle slot).
__global__ __launch_bounds__(512, 2) void fused_kernel(
        const _Float16* __restrict__ Ah, const _Float16* __restrict__ Al,
        const _Float16* __restrict__ Bh, const _Float16* __restrict__ Bl,
        float* __restrict__ C, int nGemm,
        const float* __restrict__ Uprev, int s0scan, int nScan,
        const float* __restrict__ X,
        f16x4* __restrict__ Xch, f16x4* __restrict__ Xcl, int s0cast,
        float* __restrict__ Xt4, int xtMode,
        const float* __restrict__ vf,  const float* __restrict__ vr,
        const float* __restrict__ bfv, const float* __restrict__ brv,
        float* __restrict__ Y, float* __restrict__ carry) {
    // [dbuf][mat: Ah,Al,Bh,Bl][256 rows x 32 k] f16 = 131072 B
    __shared__ _Float16 SH[2][4][256 * 32];

    const int tid = threadIdx.x;

    if ((int)blockIdx.x < nScan) {
        // ---------------- scan path (previous chunk), hidden under the GEMM ----------------
        if (tid >= 256) return;                     // waves 4..7 idle (no barriers here)
        int gid = blockIdx.x * 256 + tid;           // 0..8191 channel
        int b = gid >> 10;
        int h = gid & 1023;
        float vfh = vf[h], vrh = vr[h], bfh = bfv[h], brh = brv[h];
        const float* Ub4 = Uprev + ((size_t)(b * TB_) * K3_ + h) * 4;
        const float* Xb = X + ((size_t)b * S_ + s0scan) * H_ + h;
        float* Yb = Y + ((size_t)b * S_ + s0scan) * H_ + h;
        float c = (s0scan == 0) ? 0.f : carry[gid];

        float Af[8], Ac[8], Ar[8], Ax[8];
        float Bf[8], Bc[8], Br[8], Bx[8];
        auto LOAD = [&](int t0, float (&sf)[8], float (&sc)[8], float (&sr)[8], float (&sx)[8]) {
#pragma unroll
            for (int q = 0; q < 2; ++q) {
                const float* up = Ub4 + (size_t)((t0 >> 2) + q) * (K3_ * 4);
                float4 a  = *(const float4*)(up);
                float4 bb = *(const float4*)(up + H_ * 4);
                float4 cc = *(const float4*)(up + 2 * H_ * 4);
                sf[q*4+0]=a.x;  sf[q*4+1]=a.y;  sf[q*4+2]=a.z;  sf[q*4+3]=a.w;
                sc[q*4+0]=bb.x; sc[q*4+1]=bb.y; sc[q*4+2]=bb.z; sc[q*4+3]=bb.w;
                sr[q*4+0]=cc.x; sr[q*4+1]=cc.y; sr[q*4+2]=cc.z; sr[q*4+3]=cc.w;
            }
#pragma unroll
            for (int u = 0; u < 8; ++u) sx[u] = Xb[(size_t)(t0 + u) * H_];
        };
        auto COMP = [&](int t0, float (&sf)[8], float (&sc)[8], float (&sr)[8], float (&sx)[8]) {
#pragma unroll
            for (int u = 0; u < 8; ++u) {
                float zf = sf[u] + bfh + vfh * c;
                float zr = sr[u] + brh + vrh * c;
                float xc = sc[u];
                float ft = __builtin_amdgcn_rcpf(1.f + __expf(-zf));
                float rt = __builtin_amdgcn_rcpf(1.f + __expf(-zr));
                c = ft * (c - xc) + xc;
                float xv = sx[u];
                float ht = rt * (c - xv) + xv;
                Yb[(size_t)(t0 + u) * H_] = ht;
            }
        };
        LOAD(0, Af, Ac, Ar, Ax);
        for (int t0 = 0; t0 < SC_; t0 += 16) {
            LOAD(t0 + 8, Bf, Bc, Br, Bx);
            COMP(t0, Af, Ac, Ar, Ax);
            if (t0 + 16 < SC_) LOAD(t0 + 16, Af, Ac, Ar, Ax);
            COMP(t0 + 8, Bf, Bc, Br, Bx);
        }
        carry[gid] = c;
        return;
    }

    if ((int)blockIdx.x >= nScan + nGemm) {
        // ---------------- aux path (cast next chunk / xpose chunk 3) ----------------
        int ci = (int)blockIdx.x - nScan - nGemm;   // 0..31
        if (xtMode) {
            // transpose chunk-3 x into Xt4: 4096 tiles / 32 blocks = 128 tiles/block,
            // 2 teams of 256 threads, 64 lockstep iterations (block-wide barriers).
            int team = tid >> 8, ttid = tid & 255;
            float (*tile)[33] = (float (*)[33])((char*)SH + team * 4352);
            for (int it = 0; it < 64; ++it)
                xpose_tile(X, Xt4, ci * 128 + it * 2 + team, ttid, s0cast, tile);
            return;
        }
        if (s0cast < 0) return;
        const float4* X4p = (const float4*)X;
        int gid0 = ci * 512 + tid;                  // 0..16383
#pragma unroll 4
        for (int u = 0; u < 64; ++u) {
            int i  = gid0 + u * 16384;              // 0..1048575
            int r  = i >> 8;
            int c4 = i & 255;
            int b  = r >> 9;
            int sl = r & (SC_ - 1);
            float4 v = X4p[((size_t)b * S_ + s0cast + sl) * (H_ / 4) + c4];
            _Float16 h0 = (_Float16)v.x, h1 = (_Float16)v.y, h2 = (_Float16)v.z, h3 = (_Float16)v.w;
            f16x4 hv = {h0, h1, h2, h3};
            f16x4 lv = {(_Float16)(v.x - (float)h0), (_Float16)(v.y - (float)h1),
                        (_Float16)(v.z - (float)h2), (_Float16)(v.w - (float)h3)};
            size_t dst = ((size_t)b * SC_ + sl) * (H_ / 4) + c4;
            Xch[dst] = hv;
            Xcl[dst] = lv;
        }
        return;
    }

    // ---------------- GEMM path: U[m,n] = (1/WSCALE) * (AlBh + AhBl + AhBh) ----------------
    const int idxg = (int)blockIdx.x - nScan;       // 0..191
    const int bm   = (idxg / 12) * 256;
    const int bn   = (idxg % 12) * 256;
    const int lane = tid & 63;
    const int w    = tid >> 6;                      // 0..7
    const int wm   = (w >> 2) * 128;                // 2 M-rows of waves
    const int wn   = (w & 3) * 64;                  // 4 N-cols of waves
    const int K    = 1024;

    const int quad = lane >> 4;
    const int lrow = lane & 15;

    f32x4 acc[8][4];
#pragma unroll
    for (int i = 0; i < 8; ++i)
#pragma unroll
        for (int j = 0; j < 4; ++j) {
            f32x4 z = {0.f, 0.f, 0.f, 0.f};
            acc[i][j] = z;
        }

    // k-invariant LDS byte offsets for this lane's fragments (XOR involution applied)
    unsigned offB[4], offA[8];
#pragma unroll
    for (int j = 0; j < 4; ++j) {
        int r = wn + j * 16 + lrow;
        offB[j] = (unsigned)r * 64u + (unsigned)((quad ^ ((r >> 1) & 3)) << 4);
    }
#pragma unroll
    for (int i = 0; i < 8; ++i) {
        int r = wm + i * 16 + lrow;
        offA[i] = (unsigned)r * 64u + (unsigned)((quad ^ ((r >> 1) & 3)) << 4);
    }

    // STAGE: tile kt (K-offset kt*32) into buffer bi. 8 global_load_lds per thread
    // (FIFO: Ah,Al,Bh,Bl x2). XOR swizzle on the GLOBAL source column-quad
    // (global_load_lds dest must stay linear); reads apply the same involution.
    auto STAGE = [&](int kt, int bi) {
        int kk = kt * 32;
#pragma unroll
        for (int j = 0; j < 2; ++j) {
            int idx = j * 512 + tid;                // 0..1023
            int row = idx >> 2;                     // 0..255
            int kp  = (((idx & 3) ^ ((row >> 1) & 3)) << 3);
            size_t aoff = (size_t)(bm + row) * K + kk + kp;
            size_t boff = (size_t)(bn + row) * K + kk + kp;
            unsigned base = (unsigned)(j * 512 + (tid & ~63)) * 16u;  // wave-uniform bytes
            __builtin_amdgcn_global_load_lds(
                (const __attribute__((address_space(1))) void*)(Ah + aoff),
                (__attribute__((address_space(3))) void*)((char*)&SH[bi][0][0] + base), 16, 0, 0);
            __builtin_amdgcn_global_load_lds(
                (const __attribute__((address_space(1))) void*)(Al + aoff),
                (__attribute__((address_space(3))) void*)((char*)&SH[bi][1][0] + base), 16, 0, 0);
            __builtin_amdgcn_global_load_lds(
                (const __attribute__((address_space(1))) void*)(Bh + boff),
                (__attribute__((address_space(3))) void*)((char*)&SH[bi][2][0] + base), 16, 0, 0);
            __builtin_amdgcn_global_load_lds(
                (const __attribute__((address_space(1))) void*)(Bl + boff),
                (__attribute__((address_space(3))) void*)((char*)&SH[bi][3][0] + base), 16, 0, 0);
        }
    };

    // COMPUTE: term-major per i-half. Fragments hoisted; dependent MFMAs on the same
    // acc are 16 independent MFMAs apart. Per-acc term order: lbh -> hbl -> hbh.
    auto COMPUTE = [&](int bi) {
        const char* pAh = (const char*)&SH[bi][0][0];
        const char* pAl = (const char*)&SH[bi][1][0];
        const char* pBh = (const char*)&SH[bi][2][0];
        const char* pBl = (const char*)&SH[bi][3][0];
        f16x8 bhf[4], blf[4];
#pragma unroll
        for (int j = 0; j < 4; ++j) {
            bhf[j] = *(const f16x8*)(pBh + offB[j]);
            blf[j] = *(const f16x8*)(pBl + offB[j]);
        }
#pragma unroll
        for (int half = 0; half < 2; ++half) {
            f16x8 a_h[4], a_l[4];
#pragma unroll
            for (int i2 = 0; i2 < 4; ++i2) {
                a_h[i2] = *(const f16x8*)(pAh + offA[half * 4 + i2]);
                a_l[i2] = *(const f16x8*)(pAl + offA[half * 4 + i2]);
            }
#pragma unroll
            for (int i2 = 0; i2 < 4; ++i2)
#pragma unroll
                for (int j = 0; j < 4; ++j)
                    acc[half*4+i2][j] = __builtin_amdgcn_mfma_f32_16x16x32_f16(
                        a_l[i2], bhf[j], acc[half*4+i2][j], 0, 0, 0);
#pragma unroll
            for (int i2 = 0; i2 < 4; ++i2)
#pragma unroll
                for (int j = 0; j < 4; ++j)
                    acc[half*4+i2][j] = __builtin_amdgcn_mfma_f32_16x16x32_f16(
                        a_h[i2], blf[j], acc[half*4+i2][j], 0, 0, 0);
#pragma unroll
            for (int i2 = 0; i2 < 4; ++i2)
#pragma unroll
                for (int j = 0; j < 4; ++j)
                    acc[half*4+i2][j] = __builtin_amdgcn_mfma_f32_16x16x32_f16(
                        a_h[i2], bhf[j], acc[half*4+i2][j], 0, 0, 0);
        }
    };

    // prologue: 2 K-tiles in flight
    STAGE(0, 0);
    STAGE(1, 1);
    // main loop: wait ONLY the oldest tile (8 newer loads stay in flight across barriers)
    for (int t = 0; t < 31; ++t) {
        asm volatile("s_waitcnt vmcnt(8)" ::: "memory");
        __builtin_amdgcn_s_barrier();               // tile t fully in LDS (all waves)
        __builtin_amdgcn_sched_barrier(0);          // keep COMPUTE reads below the barrier
        COMPUTE(t & 1);
        __builtin_amdgcn_sched_barrier(0);          // keep reads above the next barrier
        __builtin_amdgcn_s_barrier();               // all waves done reading buf[t&1]
        __builtin_amdgcn_sched_barrier(0);          // keep STAGE writes below the barrier
        if (t < 30) STAGE(t + 2, t & 1);            // overwrite freed buffer
    }
    asm volatile("s_waitcnt vmcnt(0)" ::: "memory");
    __builtin_amdgcn_s_barrier();
    __builtin_amdgcn_sched_barrier(0);
    COMPUTE(1);                                     // tile 31

    // epilogue: U4 layout -> one float4 store per fragment (full-line coalesced)
    const float inv = 1.0f / WSCALE;
#pragma unroll
    for (int i = 0; i < 8; ++i)
#pragma unroll
        for (int j = 0; j < 4; ++j) {
            int row = bm + wm + i * 16 + quad * 4;  // multiple of 4
            int col = bn + wn + j * 16 + lrow;
            float4 v = {acc[i][j][0] * inv, acc[i][j][1] * inv,
                        acc[i][j][2] * inv, acc[i][j][3] * inv};
            *(float4*)(C + ((size_t)(row >> 2) * K3_ + col) * 4) = v;
        }
}

// ---------------------------------------------------------------- standalone scan (final chunk)
// 256 blocks x 32 active lanes. All four streams (f,c,r,x) read as coalesced float4
// (U4 + X4 layouts): 8 requests per 8 timesteps per lane (was 14 with strided x).
__global__ __launch_bounds__(64, 1) void scan_final_kernel(const float* __restrict__ U4,
                                                           const float* __restrict__ X4,
                                                           const float* __restrict__ vf,
                                                           const float* __restrict__ vr,
                                                           const float* __restrict__ bfv,
                                                           const float* __restrict__ brv,
                                                           float* __restrict__ Y,
                                                           float* __restrict__ Cf,
                                                           const float* __restrict__ carry,
                                                           int s0) {
    int lane = threadIdx.x;
    if (lane >= 32) return;
    int gid = blockIdx.x * 32 + lane;          // 0..8191
    int b = gid >> 10;
    int h = gid & 1023;
    float vfh = vf[h], vrh = vr[h], bfh = bfv[h], brh = brv[h];
    const float* Ub4 = U4 + ((size_t)(b * TB_) * K3_ + h) * 4;
    const float* Xb4 = X4 + ((size_t)(b * TB_) * H_ + h) * 4;
    float* Yb = Y + ((size_t)b * S_ + s0) * H_ + h;
    float c = carry[gid];

    float Af[8], Ac[8], Ar[8], Ax[8];
    float Bf[8], Bc[8], Br[8], Bx[8];
    float Cg[8], Cc[8], Cr[8], Cx[8];
    float Df[8], Dc[8], Dr[8], Dx[8];

    auto LOAD = [&](int t0, float (&sf)[8], float (&sc)[8], float (&sr)[8], float (&sx)[8]) {
#pragma unroll
        for (int q = 0; q < 2; ++q) {
            size_t tb = (size_t)((t0 >> 2) + q);
            const float* up = Ub4 + tb * (K3_ * 4);
            float4 a  = *(const float4*)(up);
            float4 bb = *(const float4*)(up + H_ * 4);
            float4 cc = *(const float4*)(up + 2 * H_ * 4);
            float4 xx = *(const float4*)(Xb4 + tb * (H_ * 4));
            sf[q*4+0]=a.x;  sf[q*4+1]=a.y;  sf[q*4+2]=a.z;  sf[q*4+3]=a.w;
            sc[q*4+0]=bb.x; sc[q*4+1]=bb.y; sc[q*4+2]=bb.z; sc[q*4+3]=bb.w;
            sr[q*4+0]=cc.x; sr[q*4+1]=cc.y; sr[q*4+2]=cc.z; sr[q*4+3]=cc.w;
            sx[q*4+0]=xx.x; sx[q*4+1]=xx.y; sx[q*4+2]=xx.z; sx[q*4+3]=xx.w;
        }
    };
    auto COMP = [&](int t0, float (&sf)[8], float (&sc)[8], float (&sr)[8], float (&sx)[8]) {
#pragma unroll
        for (int u = 0; u < 8; ++u) {
            float zf = sf[u] + bfh + vfh * c;
            float zr = sr[u] + brh + vrh * c;
            float xc = sc[u];
            float ft = __builtin_amdgcn_rcpf(1.f + __expf(-zf));
            float rt = __builtin_amdgcn_rcpf(1.f + __expf(-zr));
            c = ft * (c - xc) + xc;
            float xv = sx[u];
            float ht = rt * (c - xv) + xv;
            Yb[(size_t)(t0 + u) * H_] = ht;
        }
    };

    LOAD(0, Af, Ac, Ar, Ax);
    LOAD(8, Bf, Bc, Br, Bx);
    LOAD(16, Cg, Cc, Cr, Cx);
    for (int t0 = 0; t0 < SC_; t0 += 32) {
        LOAD(t0 + 24, Df, Dc, Dr, Dx);
        COMP(t0, Af, Ac, Ar, Ax);
        if (t0 + 32 < SC_) LOAD(t0 + 32, Af, Ac, Ar, Ax);
        COMP(t0 + 8, Bf, Bc, Br, Bx);
        if (t0 + 40 < SC_) LOAD(t0 + 40, Bf, Bc, Br, Bx);
        COMP(t0 + 16, Cg, Cc, Cr, Cx);
        if (t0 + 48 < SC_) LOAD(t0 + 48, Cg, Cc, Cr, Cx);
        COMP(t0 + 24, Df, Dc, Dr, Dx);
    }
    Cf[(size_t)b * H_ + h] = c;
}

// ---------------------------------------------------------------- launcher
extern "C" void kernel_launch(void* const* d_in, const int* in_sizes, int n_in,
                              void* d_out, int out_size, void* d_ws, size_t ws_size,
                              hipStream_t stream) {
    const float* x  = (const float*)d_in[0];
    const float* W  = (const float*)d_in[1];
    const float* vf = (const float*)d_in[2];
    const float* vr = (const float*)d_in[3];
    const float* bf = (const float*)d_in[4];
    const float* br = (const float*)d_in[5];
    float* y  = (float*)d_out;
    float* cf = y + (size_t)B_ * S_ * H_;

    // ws layout (bytes):
    //   U0 @0            50,331,648
    //   U1 @50,331,648   50,331,648
    //   xh0 @100,663,296  8,388,608   } reused (contiguous 16 MiB) as Xt4 once the
    //   xl0 @109,051,904  8,388,608   } chunk-2 planes are dead (after fused i=2/i=3)
    //   Wth @117,440,512  6,291,456
    //   Wtl @123,731,968  6,291,456
    //   carry @130,023,424   32,768
    //   xh1 @130,056,192  8,388,608   (big-ws only)
    //   xl1 @138,444,800  8,388,608   (end 146,833,408 — confirmed available)
    char* base = (char*)d_ws;
    float* U0 = (float*)base;
    float* U1 = (float*)(base + 50331648);
    _Float16* xh0 = (_Float16*)(base + 100663296);
    _Float16* xl0 = (_Float16*)(base + 109051904);
    _Float16* Wth = (_Float16*)(base + 117440512);
    _Float16* Wtl = (_Float16*)(base + 123731968);
    float* carry  = (float*)(base + 130023424);
    _Float16* xh1 = (_Float16*)(base + 130056192);
    _Float16* xl1 = (_Float16*)(base + 138444800);
    float* Xt4    = (float*)(base + 100663296);    // overlays xh0+xl0: 16,777,216 B exact

    const bool big = ws_size >= 146833408ULL;      // constant across calls -> graph-safe
    float* Ubuf[2] = {U0, U1};
    _Float16* Xh[2] = {xh0, big ? xh1 : xh0};
    _Float16* Xl[2] = {xl0, big ? xl1 : xl0};

    // prep: transW + cast chunk0 into xbuf0
    prep_kernel<<<3072 + 1024, 256, 0, stream>>>(W, Wth, Wtl, (const float4*)x,
                                                 (f16x4*)xh0, (f16x4*)xl0);

    for (int i = 0; i < 4; ++i) {
        const int nScan = (i >= 1) ? 32 : 0;
        int nCast = 0, s0C = -1, nxt = i, xtM = 0;
        if (big) {
            nCast = 32;
            if (i < 3) { nxt = i + 1; s0C = (i + 1) * SC_; }
            else       { s0C = 3 * SC_; xtM = 1; }  // idle aux slot -> xpose chunk 3
        } else if (i >= 1) {
            castx_kernel<<<1024, 256, 0, stream>>>((const float4*)x, (f16x4*)xh0,
                                                   (f16x4*)xl0, i * SC_);
        }
        const _Float16* Ahp = Xh[big ? (i & 1) : 0];
        const _Float16* Alp = Xl[big ? (i & 1) : 0];
        fused_kernel<<<nScan + NGEMM_ + nCast, 512, 0, stream>>>(
            Ahp, Alp, Wth, Wtl, Ubuf[i & 1], NGEMM_,
            (i >= 1) ? Ubuf[(i - 1) & 1] : Ubuf[0],
            (i >= 1) ? (i - 1) * SC_ : 0, nScan,
            x, (f16x4*)Xh[nxt & 1], (f16x4*)Xl[nxt & 1], s0C,
            Xt4, xtM, vf, vr, bf, br, y, carry);
    }

    // small-ws: chunk-3 planes (in xh0/xl0) are dead after fused i=3 -> transpose x there now
    if (!big) xpose_kernel<<<1024, 256, 0, stream>>>(x, Xt4, 3 * SC_);

    // final scan: chunk 3, all streams coalesced float4, writes Cf
    scan_final_kernel<<<256, 64, 0, stream>>>(Ubuf[1], Xt4, vf, vr, bf, br, y, cf, carry, 3 * SC_);
}

// Round 11
// 450.220 us; speedup vs baseline: 1.1235x; 1.0726x over previous
//
#include <hip/hip_runtime.h>
#include <cstdint>
#include <cstddef>

#define B_   8
#define S_   2048
#define H_   1024
#define K3_  3072              // 3*H
#define SC_  512               // chunk length
#define TB_  (SC_ / 4)         // 128 t-blocks (of 4 timesteps) per chunk
#define WSCALE 32.0f           // pre-scale W so f16 lo-plane stays normal-range
#define NGEMM_ 192             // (4096/256) * (3072/256)

typedef __attribute__((ext_vector_type(8))) _Float16 f16x8;
typedef __attribute__((ext_vector_type(4))) _Float16 f16x4;
typedef __attribute__((ext_vector_type(4))) float f32x4;

// U layout: t-interleaved-transposed U4[b][tb][k3][4] (tb=t>>2): GEMM epilogue stores
// float4 (full-line coalesced), scan reads float4 = 4 timesteps/channel.
// X4 layout (chunk 3 only): X4[b][tb][h][4] for scan_final float4 reads.

// --------------------------------------------- cast body (256-thr blocks; prep + fallback)
__device__ __forceinline__ void cast_body(const float4* __restrict__ X,
                                          f16x4* __restrict__ Xh, f16x4* __restrict__ Xl,
                                          int ci, int tid, int s0) {
    const int nthr = (B_ * SC_ * H_) >> 4;
    int i0 = ci * 256 + tid;
#pragma unroll
    for (int u = 0; u < 4; ++u) {
        int i  = i0 + u * nthr;
        int r  = i >> 8;
        int c4 = i & 255;
        int b  = r >> 9;
        int sl = r & (SC_ - 1);
        size_t src = ((size_t)b * S_ + s0 + sl) * (H_ / 4) + c4;
        float4 v = X[src];
        _Float16 h0 = (_Float16)v.x, h1 = (_Float16)v.y, h2 = (_Float16)v.z, h3 = (_Float16)v.w;
        f16x4 hv = {h0, h1, h2, h3};
        f16x4 lv = {(_Float16)(v.x - (float)h0), (_Float16)(v.y - (float)h1),
                    (_Float16)(v.z - (float)h2), (_Float16)(v.w - (float)h3)};
        size_t dst = ((size_t)b * SC_ + sl) * (H_ / 4) + c4;
        Xh[dst] = hv;
        Xl[dst] = lv;
    }
}

// --------------------------------------------- xpose tile: one 32(t) x 32(h) tile -> X4
// 256-thread team; caller provides a 32x33 float LDS scratch. Two __syncthreads per call
// (all teams in a block must call in lockstep).
__device__ __forceinline__ void xpose_tile(const float* __restrict__ X, float* __restrict__ X4,
                                           int tg, int ttid, int s0, float (*tile)[33]) {
    int tx = ttid & 31, ty = ttid >> 5;    // ty 0..7
    int b    = tg >> 9;                    // 512 tiles per batch
    int tt   = tg & 511;
    int tb32 = tt >> 5;                    // 32-step t block, 0..15
    int hb   = tt & 31;                    // 32-ch h block, 0..31
#pragma unroll
    for (int i2 = 0; i2 < 4; ++i2) {
        int t = tb32 * 32 + ty + i2 * 8;
        tile[ty + i2 * 8][tx] = X[((size_t)b * S_ + s0 + t) * H_ + hb * 32 + tx];
    }
    __syncthreads();
    int h  = hb * 32 + tx;
    int tb = tb32 * 8 + ty;                // tb within chunk
    float4 v = {tile[ty * 4 + 0][tx], tile[ty * 4 + 1][tx],
                tile[ty * 4 + 2][tx], tile[ty * 4 + 3][tx]};
    *(float4*)(X4 + ((size_t)(b * TB_ + tb) * H_ + h) * 4) = v;
    __syncthreads();
}

// --------------------------------------------- standalone cast (small-ws fallback path)
__global__ __launch_bounds__(256) void castx_kernel(const float4* __restrict__ X,
                                                    f16x4* __restrict__ Xh,
                                                    f16x4* __restrict__ Xl, int s0) {
    cast_body(X, Xh, Xl, blockIdx.x, threadIdx.x, s0);
}

// --------------------------------------------- standalone x-transpose (small-ws fallback)
__global__ __launch_bounds__(256) void xpose_kernel(const float* __restrict__ X,
                                                    float* __restrict__ X4, int s0) {
    __shared__ float tile[32][33];
#pragma unroll
    for (int it = 0; it < 4; ++it)
        xpose_tile(X, X4, (int)blockIdx.x * 4 + it, threadIdx.x, s0, tile);
}

// --------------------------------------------- prep: transW (blocks 0..3071) + cast chunk0
__global__ __launch_bounds__(256) void prep_kernel(const float* __restrict__ W,
                                                   _Float16* __restrict__ Wth,
                                                   _Float16* __restrict__ Wtl,
                                                   const float4* __restrict__ X,
                                                   f16x4* __restrict__ Xh,
                                                   f16x4* __restrict__ Xl) {
    __shared__ float tile[32][33];
    if ((int)blockIdx.x < 3072) {
        int idx = blockIdx.x;
        int bc  = (idx % 96) * 32;
        int brr = (idx / 96) * 32;
        int tx = threadIdx.x & 31;
        int ty = threadIdx.x >> 5;
#pragma unroll
        for (int i = 0; i < 4; ++i) {
            int r = ty + i * 8;
            tile[r][tx] = W[(size_t)(brr + r) * K3_ + bc + tx];
        }
        __syncthreads();
#pragma unroll
        for (int i = 0; i < 4; ++i) {
            int r = ty + i * 8;
            float v = tile[tx][r] * WSCALE;
            _Float16 h = (_Float16)v;
            _Float16 l = (_Float16)(v - (float)h);
            Wth[(size_t)(bc + r) * H_ + brr + tx] = h;
            Wtl[(size_t)(bc + r) * H_ + brr + tx] = l;
        }
    } else {
        cast_body(X, Xh, Xl, (int)blockIdx.x - 3072, threadIdx.x, 0);
    }
}

// ---------------------------------------------------------------- fused GEMM + scan + cast/xpose
// Grid (big-ws): 32 scan + 192 GEMM + 32 aux = 256 blocks x 512 thr = 1 block/CU.
// GEMM: 256x256 tile, BK=32, 8 waves (2M x 4N), double-buffered LDS (128 KB).
// R10/R11 K-loop: ONE barrier per K-tile (was 2). Per iteration t:
//   vmcnt(0)            — this wave's 8 tile-t loads done (issued a full iteration ago,
//                         mostly L2-resident; nothing newer outstanding at this point)
//   s_barrier           — (a) tile t complete in LDS for all waves;
//                         (b) releases buf[t&1^1]: every wave's ds_reads of it (iter t-1)
//                         completed before its MFMAs, hence before it reached this barrier
//   sched_barrier(0)    — pin stage issues and ds_reads below the barrier
//   STAGE(t+1 -> other buf) interleaved with COMPUTE(buf[t&1]) by the scheduler —
//   stage issue now overlaps the MFMA region instead of sitting between two barriers.
__global__ __launch_bounds__(512, 2) void fused_kernel(
        const _Float16* __restrict__ Ah, const _Float16* __restrict__ Al,
        const _Float16* __restrict__ Bh, const _Float16* __restrict__ Bl,
        float* __restrict__ C, int nGemm,
        const float* __restrict__ Uprev, int s0scan, int nScan,
        const float* __restrict__ X,
        f16x4* __restrict__ Xch, f16x4* __restrict__ Xcl, int s0cast,
        float* __restrict__ Xt4, int xtMode,
        const float* __restrict__ vf,  const float* __restrict__ vr,
        const float* __restrict__ bfv, const float* __restrict__ brv,
        float* __restrict__ Y, float* __restrict__ carry) {
    // [dbuf][mat: Ah,Al,Bh,Bl][256 rows x 32 k] f16 = 131072 B
    __shared__ _Float16 SH[2][4][256 * 32];

    const int tid = threadIdx.x;

    if ((int)blockIdx.x < nScan) {
        // ---------------- scan path (previous chunk), hidden under the GEMM ----------------
        if (tid >= 256) return;                     // waves 4..7 idle (no barriers here)
        int gid = blockIdx.x * 256 + tid;           // 0..8191 channel
        int b = gid >> 10;
        int h = gid & 1023;
        float vfh = vf[h], vrh = vr[h], bfh = bfv[h], brh = brv[h];
        const float* Ub4 = Uprev + ((size_t)(b * TB_) * K3_ + h) * 4;
        const float* Xb = X + ((size_t)b * S_ + s0scan) * H_ + h;
        float* Yb = Y + ((size_t)b * S_ + s0scan) * H_ + h;
        float c = (s0scan == 0) ? 0.f : carry[gid];

        float Af[8], Ac[8], Ar[8], Ax[8];
        float Bf[8], Bc[8], Br[8], Bx[8];
        auto LOAD = [&](int t0, float (&sf)[8], float (&sc)[8], float (&sr)[8], float (&sx)[8]) {
#pragma unroll
            for (int q = 0; q < 2; ++q) {
                const float* up = Ub4 + (size_t)((t0 >> 2) + q) * (K3_ * 4);
                float4 a  = *(const float4*)(up);
                float4 bb = *(const float4*)(up + H_ * 4);
                float4 cc = *(const float4*)(up + 2 * H_ * 4);
                sf[q*4+0]=a.x;  sf[q*4+1]=a.y;  sf[q*4+2]=a.z;  sf[q*4+3]=a.w;
                sc[q*4+0]=bb.x; sc[q*4+1]=bb.y; sc[q*4+2]=bb.z; sc[q*4+3]=bb.w;
                sr[q*4+0]=cc.x; sr[q*4+1]=cc.y; sr[q*4+2]=cc.z; sr[q*4+3]=cc.w;
            }
#pragma unroll
            for (int u = 0; u < 8; ++u) sx[u] = Xb[(size_t)(t0 + u) * H_];
        };
        auto COMP = [&](int t0, float (&sf)[8], float (&sc)[8], float (&sr)[8], float (&sx)[8]) {
#pragma unroll
            for (int u = 0; u < 8; ++u) {
                float zf = sf[u] + bfh + vfh * c;
                float zr = sr[u] + brh + vrh * c;
                float xc = sc[u];
                float ft = __builtin_amdgcn_rcpf(1.f + __expf(-zf));
                float rt = __builtin_amdgcn_rcpf(1.f + __expf(-zr));
                c = ft * (c - xc) + xc;
                float xv = sx[u];
                float ht = rt * (c - xv) + xv;
                Yb[(size_t)(t0 + u) * H_] = ht;
            }
        };
        LOAD(0, Af, Ac, Ar, Ax);
        for (int t0 = 0; t0 < SC_; t0 += 16) {
            LOAD(t0 + 8, Bf, Bc, Br, Bx);
            COMP(t0, Af, Ac, Ar, Ax);
            if (t0 + 16 < SC_) LOAD(t0 + 16, Af, Ac, Ar, Ax);
            COMP(t0 + 8, Bf, Bc, Br, Bx);
        }
        carry[gid] = c;
        return;
    }

    if ((int)blockIdx.x >= nScan + nGemm) {
        // ---------------- aux path (cast next chunk / xpose chunk 3) ----------------
        int ci = (int)blockIdx.x - nScan - nGemm;   // 0..31
        if (xtMode) {
            // transpose chunk-3 x into Xt4: 4096 tiles / 32 blocks = 128 tiles/block,
            // 2 teams of 256 threads, 64 lockstep iterations (block-wide barriers).
            int team = tid >> 8, ttid = tid & 255;
            float (*tile)[33] = (float (*)[33])((char*)SH + team * 4352);
            for (int it = 0; it < 64; ++it)
                xpose_tile(X, Xt4, ci * 128 + it * 2 + team, ttid, s0cast, tile);
            return;
        }
        if (s0cast < 0) return;
        const float4* X4p = (const float4*)X;
        int gid0 = ci * 512 + tid;                  // 0..16383
#pragma unroll 4
        for (int u = 0; u < 64; ++u) {
            int i  = gid0 + u * 16384;              // 0..1048575
            int r  = i >> 8;
            int c4 = i & 255;
            int b  = r >> 9;
            int sl = r & (SC_ - 1);
            float4 v = X4p[((size_t)b * S_ + s0cast + sl) * (H_ / 4) + c4];
            _Float16 h0 = (_Float16)v.x, h1 = (_Float16)v.y, h2 = (_Float16)v.z, h3 = (_Float16)v.w;
            f16x4 hv = {h0, h1, h2, h3};
            f16x4 lv = {(_Float16)(v.x - (float)h0), (_Float16)(v.y - (float)h1),
                        (_Float16)(v.z - (float)h2), (_Float16)(v.w - (float)h3)};
            size_t dst = ((size_t)b * SC_ + sl) * (H_ / 4) + c4;
            Xch[dst] = hv;
            Xcl[dst] = lv;
        }
        return;
    }

    // ---------------- GEMM path: U[m,n] = (1/WSCALE) * (AlBh + AhBl + AhBh) ----------------
    const int idxg = (int)blockIdx.x - nScan;       // 0..191
    const int bm   = (idxg / 12) * 256;
    const int bn   = (idxg % 12) * 256;
    const int lane = tid & 63;
    const int w    = tid >> 6;                      // 0..7
    const int wm   = (w >> 2) * 128;                // 2 M-rows of waves
    const int wn   = (w & 3) * 64;                  // 4 N-cols of waves
    const int K    = 1024;

    const int quad = lane >> 4;
    const int lrow = lane & 15;

    f32x4 acc[8][4];
#pragma unroll
    for (int i = 0; i < 8; ++i)
#pragma unroll
        for (int j = 0; j < 4; ++j) {
            f32x4 z = {0.f, 0.f, 0.f, 0.f};
            acc[i][j] = z;
        }

    // k-invariant LDS byte offsets for this lane's fragments (XOR involution applied)
    unsigned offB[4], offA[8];
#pragma unroll
    for (int j = 0; j < 4; ++j) {
        int r = wn + j * 16 + lrow;
        offB[j] = (unsigned)r * 64u + (unsigned)((quad ^ ((r >> 1) & 3)) << 4);
    }
#pragma unroll
    for (int i = 0; i < 8; ++i) {
        int r = wm + i * 16 + lrow;
        offA[i] = (unsigned)r * 64u + (unsigned)((quad ^ ((r >> 1) & 3)) << 4);
    }

    // STAGE: tile kt (K-offset kt*32) into buffer bi. 8 global_load_lds per thread
    // (FIFO: Ah,Al,Bh,Bl x2). XOR swizzle on the GLOBAL source column-quad
    // (global_load_lds dest must stay linear); reads apply the same involution.
    auto STAGE = [&](int kt, int bi) {
        int kk = kt * 32;
#pragma unroll
        for (int j = 0; j < 2; ++j) {
            int idx = j * 512 + tid;                // 0..1023
            int row = idx >> 2;                     // 0..255
            int kp  = (((idx & 3) ^ ((row >> 1) & 3)) << 3);
            size_t aoff = (size_t)(bm + row) * K + kk + kp;
            size_t boff = (size_t)(bn + row) * K + kk + kp;
            unsigned base = (unsigned)(j * 512 + (tid & ~63)) * 16u;  // wave-uniform bytes
            __builtin_amdgcn_global_load_lds(
                (const __attribute__((address_space(1))) void*)(Ah + aoff),
                (__attribute__((address_space(3))) void*)((char*)&SH[bi][0][0] + base), 16, 0, 0);
            __builtin_amdgcn_global_load_lds(
                (const __attribute__((address_space(1))) void*)(Al + aoff),
                (__attribute__((address_space(3))) void*)((char*)&SH[bi][1][0] + base), 16, 0, 0);
            __builtin_amdgcn_global_load_lds(
                (const __attribute__((address_space(1))) void*)(Bh + boff),
                (__attribute__((address_space(3))) void*)((char*)&SH[bi][2][0] + base), 16, 0, 0);
            __builtin_amdgcn_global_load_lds(
                (const __attribute__((address_space(1))) void*)(Bl + boff),
                (__attribute__((address_space(3))) void*)((char*)&SH[bi][3][0] + base), 16, 0, 0);
        }
    };

    // COMPUTE: term-major per i-half. Fragments hoisted; dependent MFMAs on the same
    // acc are 16 independent MFMAs apart. Per-acc term order: lbh -> hbl -> hbh.
    auto COMPUTE = [&](int bi) {
        const char* pAh = (const char*)&SH[bi][0][0];
        const char* pAl = (const char*)&SH[bi][1][0];
        const char* pBh = (const char*)&SH[bi][2][0];
        const char* pBl = (const char*)&SH[bi][3][0];
        f16x8 bhf[4], blf[4];
#pragma unroll
        for (int j = 0; j < 4; ++j) {
            bhf[j] = *(const f16x8*)(pBh + offB[j]);
            blf[j] = *(const f16x8*)(pBl + offB[j]);
        }
#pragma unroll
        for (int half = 0; half < 2; ++half) {
            f16x8 a_h[4], a_l[4];
#pragma unroll
            for (int i2 = 0; i2 < 4; ++i2) {
                a_h[i2] = *(const f16x8*)(pAh + offA[half * 4 + i2]);
                a_l[i2] = *(const f16x8*)(pAl + offA[half * 4 + i2]);
            }
#pragma unroll
            for (int i2 = 0; i2 < 4; ++i2)
#pragma unroll
                for (int j = 0; j < 4; ++j)
                    acc[half*4+i2][j] = __builtin_amdgcn_mfma_f32_16x16x32_f16(
                        a_l[i2], bhf[j], acc[half*4+i2][j], 0, 0, 0);
#pragma unroll
            for (int i2 = 0; i2 < 4; ++i2)
#pragma unroll
                for (int j = 0; j < 4; ++j)
                    acc[half*4+i2][j] = __builtin_amdgcn_mfma_f32_16x16x32_f16(
                        a_h[i2], blf[j], acc[half*4+i2][j], 0, 0, 0);
#pragma unroll
            for (int i2 = 0; i2 < 4; ++i2)
#pragma unroll
                for (int j = 0; j < 4; ++j)
                    acc[half*4+i2][j] = __builtin_amdgcn_mfma_f32_16x16x32_f16(
                        a_h[i2], bhf[j], acc[half*4+i2][j], 0, 0, 0);
        }
    };

    // prologue: stage tile 0 only (t+1-ahead schedule)
    STAGE(0, 0);
    // main loop: ONE barrier per K-tile; stage of t+1 overlaps compute of t.
    for (int t = 0; t < 32; ++t) {
        asm volatile("s_waitcnt vmcnt(0)" ::: "memory");  // own tile-t loads done
        __builtin_amdgcn_s_barrier();               // tile t ready; buf[other] released
        __builtin_amdgcn_sched_barrier(0);          // pin stage/ds_reads below barrier
        if (t < 31) STAGE(t + 1, (t & 1) ^ 1);      // into the buffer freed above
        COMPUTE(t & 1);
    }

    // epilogue: U4 layout -> one float4 store per fragment (full-line coalesced)
    const float inv = 1.0f / WSCALE;
#pragma unroll
    for (int i = 0; i < 8; ++i)
#pragma unroll
        for (int j = 0; j < 4; ++j) {
            int row = bm + wm + i * 16 + quad * 4;  // multiple of 4
            int col = bn + wn + j * 16 + lrow;
            float4 v = {acc[i][j][0] * inv, acc[i][j][1] * inv,
                        acc[i][j][2] * inv, acc[i][j][3] * inv};
            *(float4*)(C + ((size_t)(row >> 2) * K3_ + col) * 4) = v;
        }
}

// ---------------------------------------------------------------- standalone scan (final chunk)
// 256 blocks x 32 active lanes. All four streams (f,c,r,x) read as coalesced float4
// (U4 + X4 layouts).
__global__ __launch_bounds__(64, 1) void scan_final_kernel(const float* __restrict__ U4,
                                                           const float* __restrict__ X4,
                                                           const float* __restrict__ vf,
                                                           const float* __restrict__ vr,
                                                           const float* __restrict__ bfv,
                                                           const float* __restrict__ brv,
                                                           float* __restrict__ Y,
                                                           float* __restrict__ Cf,
                                                           const float* __restrict__ carry,
                                                           int s0) {
    int lane = threadIdx.x;
    if (lane >= 32) return;
    int gid = blockIdx.x * 32 + lane;          // 0..8191
    int b = gid >> 10;
    int h = gid & 1023;
    float vfh = vf[h], vrh = vr[h], bfh = bfv[h], brh = brv[h];
    const float* Ub4 = U4 + ((size_t)(b * TB_) * K3_ + h) * 4;
    const float* Xb4 = X4 + ((size_t)(b * TB_) * H_ + h) * 4;
    float* Yb = Y + ((size_t)b * S_ + s0) * H_ + h;
    float c = carry[gid];

    float Af[8], Ac[8], Ar[8], Ax[8];
    float Bf[8], Bc[8], Br[8], Bx[8];
    float Cg[8], Cc[8], Cr[8], Cx[8];
    float Df[8], Dc[8], Dr[8], Dx[8];

    auto LOAD = [&](int t0, float (&sf)[8], float (&sc)[8], float (&sr)[8], float (&sx)[8]) {
#pragma unroll
        for (int q = 0; q < 2; ++q) {
            size_t tb = (size_t)((t0 >> 2) + q);
            const float* up = Ub4 + tb * (K3_ * 4);
            float4 a  = *(const float4*)(up);
            float4 bb = *(const float4*)(up + H_ * 4);
            float4 cc = *(const float4*)(up + 2 * H_ * 4);
            float4 xx = *(const float4*)(Xb4 + tb * (H_ * 4));
            sf[q*4+0]=a.x;  sf[q*4+1]=a.y;  sf[q*4+2]=a.z;  sf[q*4+3]=a.w;
            sc[q*4+0]=bb.x; sc[q*4+1]=bb.y; sc[q*4+2]=bb.z; sc[q*4+3]=bb.w;
            sr[q*4+0]=cc.x; sr[q*4+1]=cc.y; sr[q*4+2]=cc.z; sr[q*4+3]=cc.w;
            sx[q*4+0]=xx.x; sx[q*4+1]=xx.y; sx[q*4+2]=xx.z; sx[q*4+3]=xx.w;
        }
    };
    auto COMP = [&](int t0, float (&sf)[8], float (&sc)[8], float (&sr)[8], float (&sx)[8]) {
#pragma unroll
        for (int u = 0; u < 8; ++u) {
            float zf = sf[u] + bfh + vfh * c;
            float zr = sr[u] + brh + vrh * c;
            float xc = sc[u];
            float ft = __builtin_amdgcn_rcpf(1.f + __expf(-zf));
            float rt = __builtin_amdgcn_rcpf(1.f + __expf(-zr));
            c = ft * (c - xc) + xc;
            float xv = sx[u];
            float ht = rt * (c - xv) + xv;
            Yb[(size_t)(t0 + u) * H_] = ht;
        }
    };

    LOAD(0, Af, Ac, Ar, Ax);
    LOAD(8, Bf, Bc, Br, Bx);
    LOAD(16, Cg, Cc, Cr, Cx);
    for (int t0 = 0; t0 < SC_; t0 += 32) {
        LOAD(t0 + 24, Df, Dc, Dr, Dx);
        COMP(t0, Af, Ac, Ar, Ax);
        if (t0 + 32 < SC_) LOAD(t0 + 32, Af, Ac, Ar, Ax);
        COMP(t0 + 8, Bf, Bc, Br, Bx);
        if (t0 + 40 < SC_) LOAD(t0 + 40, Bf, Bc, Br, Bx);
        COMP(t0 + 16, Cg, Cc, Cr, Cx);
        if (t0 + 48 < SC_) LOAD(t0 + 48, Cg, Cc, Cr, Cx);
        COMP(t0 + 24, Df, Dc, Dr, Dx);
    }
    Cf[(size_t)b * H_ + h] = c;
}

// ---------------------------------------------------------------- launcher
extern "C" void kernel_launch(void* const* d_in, const int* in_sizes, int n_in,
                              void* d_out, int out_size, void* d_ws, size_t ws_size,
                              hipStream_t stream) {
    const float* x  = (const float*)d_in[0];
    const float* W  = (const float*)d_in[1];
    const float* vf = (const float*)d_in[2];
    const float* vr = (const float*)d_in[3];
    const float* bf = (const float*)d_in[4];
    const float* br = (const float*)d_in[5];
    float* y  = (float*)d_out;
    float* cf = y + (size_t)B_ * S_ * H_;

    // ws layout (bytes):
    //   U0 @0            50,331,648
    //   U1 @50,331,648   50,331,648
    //   xh0 @100,663,296  8,388,608   } reused (contiguous 16 MiB) as Xt4 once the
    //   xl0 @109,051,904  8,388,608   } chunk-2 planes are dead (after fused i=2/i=3)
    //   Wth @117,440,512  6,291,456
    //   Wtl @123,731,968  6,291,456
    //   carry @130,023,424   32,768
    //   xh1 @130,056,192  8,388,608   (big-ws only)
    //   xl1 @138,444,800  8,388,608   (end 146,833,408 — confirmed available)
    char* base = (char*)d_ws;
    float* U0 = (float*)base;
    float* U1 = (float*)(base + 50331648);
    _Float16* xh0 = (_Float16*)(base + 100663296);
    _Float16* xl0 = (_Float16*)(base + 109051904);
    _Float16* Wth = (_Float16*)(base + 117440512);
    _Float16* Wtl = (_Float16*)(base + 123731968);
    float* carry  = (float*)(base + 130023424);
    _Float16* xh1 = (_Float16*)(base + 130056192);
    _Float16* xl1 = (_Float16*)(base + 138444800);
    float* Xt4    = (float*)(base + 100663296);    // overlays xh0+xl0: 16,777,216 B exact

    const bool big = ws_size >= 146833408ULL;      // constant across calls -> graph-safe
    float* Ubuf[2] = {U0, U1};
    _Float16* Xh[2] = {xh0, big ? xh1 : xh0};
    _Float16* Xl[2] = {xl0, big ? xl1 : xl0};

    // prep: transW + cast chunk0 into xbuf0
    prep_kernel<<<3072 + 1024, 256, 0, stream>>>(W, Wth, Wtl, (const float4*)x,
                                                 (f16x4*)xh0, (f16x4*)xl0);

    for (int i = 0; i < 4; ++i) {
        const int nScan = (i >= 1) ? 32 : 0;
        int nCast = 0, s0C = -1, nxt = i, xtM = 0;
        if (big) {
            nCast = 32;
            if (i < 3) { nxt = i + 1; s0C = (i + 1) * SC_; }
            else       { s0C = 3 * SC_; xtM = 1; }  // idle aux slot -> xpose chunk 3
        } else if (i >= 1) {
            castx_kernel<<<1024, 256, 0, stream>>>((const float4*)x, (f16x4*)xh0,
                                                   (f16x4*)xl0, i * SC_);
        }
        const _Float16* Ahp = Xh[big ? (i & 1) : 0];
        const _Float16* Alp = Xl[big ? (i & 1) : 0];
        fused_kernel<<<nScan + NGEMM_ + nCast, 512, 0, stream>>>(
            Ahp, Alp, Wth, Wtl, Ubuf[i & 1], NGEMM_,
            (i >= 1) ? Ubuf[(i - 1) & 1] : Ubuf[0],
            (i >= 1) ? (i - 1) * SC_ : 0, nScan,
            x, (f16x4*)Xh[nxt & 1], (f16x4*)Xl[nxt & 1], s0C,
            Xt4, xtM, vf, vr, bf, br, y, carry);
    }

    // small-ws: chunk-3 planes (in xh0/xl0) are dead after fused i=3 -> transpose x there now
    if (!big) xpose_kernel<<<1024, 256, 0, stream>>>(x, Xt4, 3 * SC_);

    // final scan: chunk 3, all streams coalesced float4, writes Cf
    scan_final_kernel<<<256, 64, 0, stream>>>(Ubuf[1], Xt4, vf, vr, bf, br, y, cf, carry, 3 * SC_);
}

// Round 12
// 447.189 us; speedup vs baseline: 1.1312x; 1.0068x over previous
//
#include <hip/hip_runtime.h>
#include <cstdint>
#include <cstddef>

#define B_   8
#define S_   2048
#define H_   1024
#define K3_  3072              // 3*H
#define SC_  512               // chunk length
#define TB_  (SC_ / 4)         // 128 t-blocks (of 4 timesteps) per chunk
#define WSCALE 32.0f           // pre-scale W so f16 lo-plane stays normal-range
#define NGEMM_ 192             // (4096/256) * (3072/256)

typedef __attribute__((ext_vector_type(8))) _Float16 f16x8;
typedef __attribute__((ext_vector_type(4))) _Float16 f16x4;
typedef __attribute__((ext_vector_type(4))) float f32x4;

// U layout: t-interleaved-transposed U4[b][tb][k3][4] (tb=t>>2): GEMM epilogue stores
// float4 (full-line coalesced), scan reads float4 = 4 timesteps/channel.
// X4 layout (chunk 3 only): X4[b][tb][h][4] for scan_final float4 reads.

// --------------------------------------------- cast body (256-thr blocks; prep + fallback)
__device__ __forceinline__ void cast_body(const float4* __restrict__ X,
                                          f16x4* __restrict__ Xh, f16x4* __restrict__ Xl,
                                          int ci, int tid, int s0) {
    const int nthr = (B_ * SC_ * H_) >> 4;
    int i0 = ci * 256 + tid;
#pragma unroll
    for (int u = 0; u < 4; ++u) {
        int i  = i0 + u * nthr;
        int r  = i >> 8;
        int c4 = i & 255;
        int b  = r >> 9;
        int sl = r & (SC_ - 1);
        size_t src = ((size_t)b * S_ + s0 + sl) * (H_ / 4) + c4;
        float4 v = X[src];
        _Float16 h0 = (_Float16)v.x, h1 = (_Float16)v.y, h2 = (_Float16)v.z, h3 = (_Float16)v.w;
        f16x4 hv = {h0, h1, h2, h3};
        f16x4 lv = {(_Float16)(v.x - (float)h0), (_Float16)(v.y - (float)h1),
                    (_Float16)(v.z - (float)h2), (_Float16)(v.w - (float)h3)};
        size_t dst = ((size_t)b * SC_ + sl) * (H_ / 4) + c4;
        Xh[dst] = hv;
        Xl[dst] = lv;
    }
}

// --------------------------------------------- xpose tile: one 32(t) x 32(h) tile -> X4
// 256-thread team; caller provides a 32x33 float LDS scratch. Two __syncthreads per call
// (all teams in a block must call in lockstep).
__device__ __forceinline__ void xpose_tile(const float* __restrict__ X, float* __restrict__ X4,
                                           int tg, int ttid, int s0, float (*tile)[33]) {
    int tx = ttid & 31, ty = ttid >> 5;    // ty 0..7
    int b    = tg >> 9;                    // 512 tiles per batch
    int tt   = tg & 511;
    int tb32 = tt >> 5;                    // 32-step t block, 0..15
    int hb   = tt & 31;                    // 32-ch h block, 0..31
#pragma unroll
    for (int i2 = 0; i2 < 4; ++i2) {
        int t = tb32 * 32 + ty + i2 * 8;
        tile[ty + i2 * 8][tx] = X[((size_t)b * S_ + s0 + t) * H_ + hb * 32 + tx];
    }
    __syncthreads();
    int h  = hb * 32 + tx;
    int tb = tb32 * 8 + ty;                // tb within chunk
    float4 v = {tile[ty * 4 + 0][tx], tile[ty * 4 + 1][tx],
                tile[ty * 4 + 2][tx], tile[ty * 4 + 3][tx]};
    *(float4*)(X4 + ((size_t)(b * TB_ + tb) * H_ + h) * 4) = v;
    __syncthreads();
}

// --------------------------------------------- standalone cast (small-ws fallback path)
__global__ __launch_bounds__(256) void castx_kernel(const float4* __restrict__ X,
                                                    f16x4* __restrict__ Xh,
                                                    f16x4* __restrict__ Xl, int s0) {
    cast_body(X, Xh, Xl, blockIdx.x, threadIdx.x, s0);
}

// --------------------------------------------- standalone x-transpose (small-ws fallback)
__global__ __launch_bounds__(256) void xpose_kernel(const float* __restrict__ X,
                                                    float* __restrict__ X4, int s0) {
    __shared__ float tile[32][33];
#pragma unroll
    for (int it = 0; it < 4; ++it)
        xpose_tile(X, X4, (int)blockIdx.x * 4 + it, threadIdx.x, s0, tile);
}

// --------------------------------------------- prep: transW (blocks 0..3071) + cast chunk0
__global__ __launch_bounds__(256) void prep_kernel(const float* __restrict__ W,
                                                   _Float16* __restrict__ Wth,
                                                   _Float16* __restrict__ Wtl,
                                                   const float4* __restrict__ X,
                                                   f16x4* __restrict__ Xh,
                                                   f16x4* __restrict__ Xl) {
    __shared__ float tile[32][33];
    if ((int)blockIdx.x < 3072) {
        int idx = blockIdx.x;
        int bc  = (idx % 96) * 32;
        int brr = (idx / 96) * 32;
        int tx = threadIdx.x & 31;
        int ty = threadIdx.x >> 5;
#pragma unroll
        for (int i = 0; i < 4; ++i) {
            int r = ty + i * 8;
            tile[r][tx] = W[(size_t)(brr + r) * K3_ + bc + tx];
        }
        __syncthreads();
#pragma unroll
        for (int i = 0; i < 4; ++i) {
            int r = ty + i * 8;
            float v = tile[tx][r] * WSCALE;
            _Float16 h = (_Float16)v;
            _Float16 l = (_Float16)(v - (float)h);
            Wth[(size_t)(bc + r) * H_ + brr + tx] = h;
            Wtl[(size_t)(bc + r) * H_ + brr + tx] = l;
        }
    } else {
        cast_body(X, Xh, Xl, (int)blockIdx.x - 3072, threadIdx.x, 0);
    }
}

// ---------------------------------------------------------------- fused GEMM + scan + cast/xpose
// Grid (big-ws): 32 scan + 192 GEMM + 32 aux = 256 blocks x 512 thr = 1 block/CU.
// GEMM: 256x256 tile, BK=32, 8 waves (2M x 4N), double-buffered LDS (128 KB).
// K-loop (R11, verified): ONE barrier per K-tile; per iteration t:
//   vmcnt(0) -> s_barrier -> sched_barrier(0) -> { STAGE(t+1) ∥ COMPUTE(t) }.
__global__ __launch_bounds__(512, 2) void fused_kernel(
        const _Float16* __restrict__ Ah, const _Float16* __restrict__ Al,
        const _Float16* __restrict__ Bh, const _Float16* __restrict__ Bl,
        float* __restrict__ C, int nGemm,
        const float* __restrict__ Uprev, int s0scan, int nScan,
        const float* __restrict__ X,
        f16x4* __restrict__ Xch, f16x4* __restrict__ Xcl, int s0cast,
        float* __restrict__ Xt4, int xtMode,
        const float* __restrict__ vf,  const float* __restrict__ vr,
        const float* __restrict__ bfv, const float* __restrict__ brv,
        float* __restrict__ Y, float* __restrict__ carry) {
    // [dbuf][mat: Ah,Al,Bh,Bl][256 rows x 32 k] f16 = 131072 B
    __shared__ _Float16 SH[2][4][256 * 32];

    const int tid = threadIdx.x;

    if ((int)blockIdx.x < nScan) {
        // ---------------- scan path (previous chunk), hidden under the GEMM ----------------
        if (tid >= 256) return;                     // waves 4..7 idle (no barriers here)
        int gid = blockIdx.x * 256 + tid;           // 0..8191 channel
        int b = gid >> 10;
        int h = gid & 1023;
        float vfh = vf[h], vrh = vr[h], bfh = bfv[h], brh = brv[h];
        const float* Ub4 = Uprev + ((size_t)(b * TB_) * K3_ + h) * 4;
        const float* Xb = X + ((size_t)b * S_ + s0scan) * H_ + h;
        float* Yb = Y + ((size_t)b * S_ + s0scan) * H_ + h;
        float c = (s0scan == 0) ? 0.f : carry[gid];

        float Af[8], Ac[8], Ar[8], Ax[8];
        float Bf[8], Bc[8], Br[8], Bx[8];
        auto LOAD = [&](int t0, float (&sf)[8], float (&sc)[8], float (&sr)[8], float (&sx)[8]) {
#pragma unroll
            for (int q = 0; q < 2; ++q) {
                const float* up = Ub4 + (size_t)((t0 >> 2) + q) * (K3_ * 4);
                float4 a  = *(const float4*)(up);
                float4 bb = *(const float4*)(up + H_ * 4);
                float4 cc = *(const float4*)(up + 2 * H_ * 4);
                sf[q*4+0]=a.x;  sf[q*4+1]=a.y;  sf[q*4+2]=a.z;  sf[q*4+3]=a.w;
                sc[q*4+0]=bb.x; sc[q*4+1]=bb.y; sc[q*4+2]=bb.z; sc[q*4+3]=bb.w;
                sr[q*4+0]=cc.x; sr[q*4+1]=cc.y; sr[q*4+2]=cc.z; sr[q*4+3]=cc.w;
            }
#pragma unroll
            for (int u = 0; u < 8; ++u) sx[u] = Xb[(size_t)(t0 + u) * H_];
        };
        auto COMP = [&](int t0, float (&sf)[8], float (&sc)[8], float (&sr)[8], float (&sx)[8]) {
#pragma unroll
            for (int u = 0; u < 8; ++u) {
                float zf = sf[u] + bfh + vfh * c;
                float zr = sr[u] + brh + vrh * c;
                float xc = sc[u];
                float ft = __builtin_amdgcn_rcpf(1.f + __expf(-zf));
                float rt = __builtin_amdgcn_rcpf(1.f + __expf(-zr));
                c = ft * (c - xc) + xc;
                float xv = sx[u];
                float ht = rt * (c - xv) + xv;
                Yb[(size_t)(t0 + u) * H_] = ht;
            }
        };
        LOAD(0, Af, Ac, Ar, Ax);
        for (int t0 = 0; t0 < SC_; t0 += 16) {
            LOAD(t0 + 8, Bf, Bc, Br, Bx);
            COMP(t0, Af, Ac, Ar, Ax);
            if (t0 + 16 < SC_) LOAD(t0 + 16, Af, Ac, Ar, Ax);
            COMP(t0 + 8, Bf, Bc, Br, Bx);
        }
        carry[gid] = c;
        return;
    }

    if ((int)blockIdx.x >= nScan + nGemm) {
        // ---------------- aux path (cast next chunk / xpose chunk 3) ----------------
        int ci = (int)blockIdx.x - nScan - nGemm;   // 0..31
        if (xtMode) {
            // transpose chunk-3 x into Xt4: 4096 tiles / 32 blocks = 128 tiles/block,
            // 2 teams of 256 threads, 64 lockstep iterations (block-wide barriers).
            int team = tid >> 8, ttid = tid & 255;
            float (*tile)[33] = (float (*)[33])((char*)SH + team * 4352);
            for (int it = 0; it < 64; ++it)
                xpose_tile(X, Xt4, ci * 128 + it * 2 + team, ttid, s0cast, tile);
            return;
        }
        if (s0cast < 0) return;
        const float4* X4p = (const float4*)X;
        int gid0 = ci * 512 + tid;                  // 0..16383
#pragma unroll 4
        for (int u = 0; u < 64; ++u) {
            int i  = gid0 + u * 16384;              // 0..1048575
            int r  = i >> 8;
            int c4 = i & 255;
            int b  = r >> 9;
            int sl = r & (SC_ - 1);
            float4 v = X4p[((size_t)b * S_ + s0cast + sl) * (H_ / 4) + c4];
            _Float16 h0 = (_Float16)v.x, h1 = (_Float16)v.y, h2 = (_Float16)v.z, h3 = (_Float16)v.w;
            f16x4 hv = {h0, h1, h2, h3};
            f16x4 lv = {(_Float16)(v.x - (float)h0), (_Float16)(v.y - (float)h1),
                        (_Float16)(v.z - (float)h2), (_Float16)(v.w - (float)h3)};
            size_t dst = ((size_t)b * SC_ + sl) * (H_ / 4) + c4;
            Xch[dst] = hv;
            Xcl[dst] = lv;
        }
        return;
    }

    // ---------------- GEMM path: U[m,n] = (1/WSCALE) * (AlBh + AhBl + AhBh) ----------------
    const int idxg = (int)blockIdx.x - nScan;       // 0..191
    const int bm   = (idxg / 12) * 256;
    const int bn   = (idxg % 12) * 256;
    const int lane = tid & 63;
    const int w    = tid >> 6;                      // 0..7
    const int wm   = (w >> 2) * 128;                // 2 M-rows of waves
    const int wn   = (w & 3) * 64;                  // 4 N-cols of waves
    const int K    = 1024;

    const int quad = lane >> 4;
    const int lrow = lane & 15;

    f32x4 acc[8][4];
#pragma unroll
    for (int i = 0; i < 8; ++i)
#pragma unroll
        for (int j = 0; j < 4; ++j) {
            f32x4 z = {0.f, 0.f, 0.f, 0.f};
            acc[i][j] = z;
        }

    // k-invariant LDS byte offsets for this lane's fragments (XOR involution applied)
    unsigned offB[4], offA[8];
#pragma unroll
    for (int j = 0; j < 4; ++j) {
        int r = wn + j * 16 + lrow;
        offB[j] = (unsigned)r * 64u + (unsigned)((quad ^ ((r >> 1) & 3)) << 4);
    }
#pragma unroll
    for (int i = 0; i < 8; ++i) {
        int r = wm + i * 16 + lrow;
        offA[i] = (unsigned)r * 64u + (unsigned)((quad ^ ((r >> 1) & 3)) << 4);
    }

    // STAGE: tile kt (K-offset kt*32) into buffer bi. 8 global_load_lds per thread
    // (FIFO: Ah,Al,Bh,Bl x2). XOR swizzle on the GLOBAL source column-quad
    // (global_load_lds dest must stay linear); reads apply the same involution.
    auto STAGE = [&](int kt, int bi) {
        int kk = kt * 32;
#pragma unroll
        for (int j = 0; j < 2; ++j) {
            int idx = j * 512 + tid;                // 0..1023
            int row = idx >> 2;                     // 0..255
            int kp  = (((idx & 3) ^ ((row >> 1) & 3)) << 3);
            size_t aoff = (size_t)(bm + row) * K + kk + kp;
            size_t boff = (size_t)(bn + row) * K + kk + kp;
            unsigned base = (unsigned)(j * 512 + (tid & ~63)) * 16u;  // wave-uniform bytes
            __builtin_amdgcn_global_load_lds(
                (const __attribute__((address_space(1))) void*)(Ah + aoff),
                (__attribute__((address_space(3))) void*)((char*)&SH[bi][0][0] + base), 16, 0, 0);
            __builtin_amdgcn_global_load_lds(
                (const __attribute__((address_space(1))) void*)(Al + aoff),
                (__attribute__((address_space(3))) void*)((char*)&SH[bi][1][0] + base), 16, 0, 0);
            __builtin_amdgcn_global_load_lds(
                (const __attribute__((address_space(1))) void*)(Bh + boff),
                (__attribute__((address_space(3))) void*)((char*)&SH[bi][2][0] + base), 16, 0, 0);
            __builtin_amdgcn_global_load_lds(
                (const __attribute__((address_space(1))) void*)(Bl + boff),
                (__attribute__((address_space(3))) void*)((char*)&SH[bi][3][0] + base), 16, 0, 0);
        }
    };

    // COMPUTE: term-major per i-half. Fragments hoisted; dependent MFMAs on the same
    // acc are 16 independent MFMAs apart. Per-acc term order: lbh -> hbl -> hbh.
    auto COMPUTE = [&](int bi) {
        const char* pAh = (const char*)&SH[bi][0][0];
        const char* pAl = (const char*)&SH[bi][1][0];
        const char* pBh = (const char*)&SH[bi][2][0];
        const char* pBl = (const char*)&SH[bi][3][0];
        f16x8 bhf[4], blf[4];
#pragma unroll
        for (int j = 0; j < 4; ++j) {
            bhf[j] = *(const f16x8*)(pBh + offB[j]);
            blf[j] = *(const f16x8*)(pBl + offB[j]);
        }
#pragma unroll
        for (int half = 0; half < 2; ++half) {
            f16x8 a_h[4], a_l[4];
#pragma unroll
            for (int i2 = 0; i2 < 4; ++i2) {
                a_h[i2] = *(const f16x8*)(pAh + offA[half * 4 + i2]);
                a_l[i2] = *(const f16x8*)(pAl + offA[half * 4 + i2]);
            }
#pragma unroll
            for (int i2 = 0; i2 < 4; ++i2)
#pragma unroll
                for (int j = 0; j < 4; ++j)
                    acc[half*4+i2][j] = __builtin_amdgcn_mfma_f32_16x16x32_f16(
                        a_l[i2], bhf[j], acc[half*4+i2][j], 0, 0, 0);
#pragma unroll
            for (int i2 = 0; i2 < 4; ++i2)
#pragma unroll
                for (int j = 0; j < 4; ++j)
                    acc[half*4+i2][j] = __builtin_amdgcn_mfma_f32_16x16x32_f16(
                        a_h[i2], blf[j], acc[half*4+i2][j], 0, 0, 0);
#pragma unroll
            for (int i2 = 0; i2 < 4; ++i2)
#pragma unroll
                for (int j = 0; j < 4; ++j)
                    acc[half*4+i2][j] = __builtin_amdgcn_mfma_f32_16x16x32_f16(
                        a_h[i2], bhf[j], acc[half*4+i2][j], 0, 0, 0);
        }
    };

    // prologue: stage tile 0 only (t+1-ahead schedule)
    STAGE(0, 0);
    // main loop: ONE barrier per K-tile; stage of t+1 overlaps compute of t.
    for (int t = 0; t < 32; ++t) {
        asm volatile("s_waitcnt vmcnt(0)" ::: "memory");  // own tile-t loads done
        __builtin_amdgcn_s_barrier();               // tile t ready; buf[other] released
        __builtin_amdgcn_sched_barrier(0);          // pin stage/ds_reads below barrier
        if (t < 31) STAGE(t + 1, (t & 1) ^ 1);      // into the buffer freed above
        COMPUTE(t & 1);
    }

    // epilogue: U4 layout -> one float4 store per fragment (full-line coalesced)
    const float inv = 1.0f / WSCALE;
#pragma unroll
    for (int i = 0; i < 8; ++i)
#pragma unroll
        for (int j = 0; j < 4; ++j) {
            int row = bm + wm + i * 16 + quad * 4;  // multiple of 4
            int col = bn + wn + j * 16 + lrow;
            float4 v = {acc[i][j][0] * inv, acc[i][j][1] * inv,
                        acc[i][j][2] * inv, acc[i][j][3] * inv};
            *(float4*)(C + ((size_t)(row >> 2) * K3_ + col) * 4) = v;
        }
}

// ---------------------------------------------------------------- standalone scan (final chunk)
// 256 blocks x 32 active lanes, all streams float4 (U4 + X4 layouts).
// R12: prefetch depth doubled — 4 rolling sets of 16 timesteps (was 8): prefetch
// distance 48-64 steps, ~32 outstanding 16B requests/lane ≈ 4 MB chip-wide in flight
// (Little's law: ~4 TB/s vs ~2 before). VGPR ≈ 4x4x16 + overhead ≈ 300 < 512 (1 wave/SIMD).
__global__ __launch_bounds__(64, 1) void scan_final_kernel(const float* __restrict__ U4,
                                                           const float* __restrict__ X4,
                                                           const float* __restrict__ vf,
                                                           const float* __restrict__ vr,
                                                           const float* __restrict__ bfv,
                                                           const float* __restrict__ brv,
                                                           float* __restrict__ Y,
                                                           float* __restrict__ Cf,
                                                           const float* __restrict__ carry,
                                                           int s0) {
    int lane = threadIdx.x;
    if (lane >= 32) return;
    int gid = blockIdx.x * 32 + lane;          // 0..8191
    int b = gid >> 10;
    int h = gid & 1023;
    float vfh = vf[h], vrh = vr[h], bfh = bfv[h], brh = brv[h];
    const float* Ub4 = U4 + ((size_t)(b * TB_) * K3_ + h) * 4;
    const float* Xb4 = X4 + ((size_t)(b * TB_) * H_ + h) * 4;
    float* Yb = Y + ((size_t)b * S_ + s0) * H_ + h;
    float c = carry[gid];

    float Af[16], Ac[16], Ar[16], Ax[16];
    float Bf[16], Bc[16], Br[16], Bx[16];
    float Cg[16], Cc[16], Cr[16], Cx[16];
    float Df[16], Dc[16], Dr[16], Dx[16];

    auto LOAD = [&](int t0, float (&sf)[16], float (&sc)[16], float (&sr)[16], float (&sx)[16]) {
#pragma unroll
        for (int q = 0; q < 4; ++q) {
            size_t tb = (size_t)((t0 >> 2) + q);
            const float* up = Ub4 + tb * (K3_ * 4);
            float4 a  = *(const float4*)(up);
            float4 bb = *(const float4*)(up + H_ * 4);
            float4 cc = *(const float4*)(up + 2 * H_ * 4);
            float4 xx = *(const float4*)(Xb4 + tb * (H_ * 4));
            sf[q*4+0]=a.x;  sf[q*4+1]=a.y;  sf[q*4+2]=a.z;  sf[q*4+3]=a.w;
            sc[q*4+0]=bb.x; sc[q*4+1]=bb.y; sc[q*4+2]=bb.z; sc[q*4+3]=bb.w;
            sr[q*4+0]=cc.x; sr[q*4+1]=cc.y; sr[q*4+2]=cc.z; sr[q*4+3]=cc.w;
            sx[q*4+0]=xx.x; sx[q*4+1]=xx.y; sx[q*4+2]=xx.z; sx[q*4+3]=xx.w;
        }
    };
    auto COMP = [&](int t0, float (&sf)[16], float (&sc)[16], float (&sr)[16], float (&sx)[16]) {
#pragma unroll
        for (int u = 0; u < 16; ++u) {
            float zf = sf[u] + bfh + vfh * c;
            float zr = sr[u] + brh + vrh * c;
            float xc = sc[u];
            float ft = __builtin_amdgcn_rcpf(1.f + __expf(-zf));
            float rt = __builtin_amdgcn_rcpf(1.f + __expf(-zr));
            c = ft * (c - xc) + xc;
            float xv = sx[u];
            float ht = rt * (c - xv) + xv;
            Yb[(size_t)(t0 + u) * H_] = ht;
        }
    };

    LOAD(0,  Af, Ac, Ar, Ax);
    LOAD(16, Bf, Bc, Br, Bx);
    LOAD(32, Cg, Cc, Cr, Cx);
    for (int t0 = 0; t0 < SC_; t0 += 64) {
        LOAD(t0 + 48, Df, Dc, Dr, Dx);
        COMP(t0, Af, Ac, Ar, Ax);
        if (t0 + 64 < SC_) LOAD(t0 + 64, Af, Ac, Ar, Ax);
        COMP(t0 + 16, Bf, Bc, Br, Bx);
        if (t0 + 80 < SC_) LOAD(t0 + 80, Bf, Bc, Br, Bx);
        COMP(t0 + 32, Cg, Cc, Cr, Cx);
        if (t0 + 96 < SC_) LOAD(t0 + 96, Cg, Cc, Cr, Cx);
        COMP(t0 + 48, Df, Dc, Dr, Dx);
    }
    Cf[(size_t)b * H_ + h] = c;
}

// ---------------------------------------------------------------- launcher
extern "C" void kernel_launch(void* const* d_in, const int* in_sizes, int n_in,
                              void* d_out, int out_size, void* d_ws, size_t ws_size,
                              hipStream_t stream) {
    const float* x  = (const float*)d_in[0];
    const float* W  = (const float*)d_in[1];
    const float* vf = (const float*)d_in[2];
    const float* vr = (const float*)d_in[3];
    const float* bf = (const float*)d_in[4];
    const float* br = (const float*)d_in[5];
    float* y  = (float*)d_out;
    float* cf = y + (size_t)B_ * S_ * H_;

    // ws layout (bytes):
    //   U0 @0            50,331,648
    //   U1 @50,331,648   50,331,648
    //   xh0 @100,663,296  8,388,608   } reused (contiguous 16 MiB) as Xt4 once the
    //   xl0 @109,051,904  8,388,608   } chunk-2 planes are dead (after fused i=2/i=3)
    //   Wth @117,440,512  6,291,456
    //   Wtl @123,731,968  6,291,456
    //   carry @130,023,424   32,768
    //   xh1 @130,056,192  8,388,608   (big-ws only)
    //   xl1 @138,444,800  8,388,608   (end 146,833,408 — confirmed available)
    char* base = (char*)d_ws;
    float* U0 = (float*)base;
    float* U1 = (float*)(base + 50331648);
    _Float16* xh0 = (_Float16*)(base + 100663296);
    _Float16* xl0 = (_Float16*)(base + 109051904);
    _Float16* Wth = (_Float16*)(base + 117440512);
    _Float16* Wtl = (_Float16*)(base + 123731968);
    float* carry  = (float*)(base + 130023424);
    _Float16* xh1 = (_Float16*)(base + 130056192);
    _Float16* xl1 = (_Float16*)(base + 138444800);
    float* Xt4    = (float*)(base + 100663296);    // overlays xh0+xl0: 16,777,216 B exact

    const bool big = ws_size >= 146833408ULL;      // constant across calls -> graph-safe
    float* Ubuf[2] = {U0, U1};
    _Float16* Xh[2] = {xh0, big ? xh1 : xh0};
    _Float16* Xl[2] = {xl0, big ? xl1 : xl0};

    // prep: transW + cast chunk0 into xbuf0
    prep_kernel<<<3072 + 1024, 256, 0, stream>>>(W, Wth, Wtl, (const float4*)x,
                                                 (f16x4*)xh0, (f16x4*)xl0);

    for (int i = 0; i < 4; ++i) {
        const int nScan = (i >= 1) ? 32 : 0;
        int nCast = 0, s0C = -1, nxt = i, xtM = 0;
        if (big) {
            nCast = 32;
            if (i < 3) { nxt = i + 1; s0C = (i + 1) * SC_; }
            else       { s0C = 3 * SC_; xtM = 1; }  // idle aux slot -> xpose chunk 3
        } else if (i >= 1) {
            castx_kernel<<<1024, 256, 0, stream>>>((const float4*)x, (f16x4*)xh0,
                                                   (f16x4*)xl0, i * SC_);
        }
        const _Float16* Ahp = Xh[big ? (i & 1) : 0];
        const _Float16* Alp = Xl[big ? (i & 1) : 0];
        fused_kernel<<<nScan + NGEMM_ + nCast, 512, 0, stream>>>(
            Ahp, Alp, Wth, Wtl, Ubuf[i & 1], NGEMM_,
            (i >= 1) ? Ubuf[(i - 1) & 1] : Ubuf[0],
            (i >= 1) ? (i - 1) * SC_ : 0, nScan,
            x, (f16x4*)Xh[nxt & 1], (f16x4*)Xl[nxt & 1], s0C,
            Xt4, xtM, vf, vr, bf, br, y, carry);
    }

    // small-ws: chunk-3 planes (in xh0/xl0) are dead after fused i=3 -> transpose x there now
    if (!big) xpose_kernel<<<1024, 256, 0, stream>>>(x, Xt4, 3 * SC_);

    // final scan: chunk 3, all streams coalesced float4, writes Cf
    scan_final_kernel<<<256, 64, 0, stream>>>(Ubuf[1], Xt4, vf, vr, bf, br, y, cf, carry, 3 * SC_);
}